// Round 13
// baseline (6128.034 us; speedup 1.0000x reference)
//
#include <hip/hip_runtime.h>
#include <hip/hip_bf16.h>

#define WIDTH 64
#define KW 1024
#define DEPTH 6
#define NN 10000
#define NE 100000
#define E_PAD 100096          // 782 * 128
#define MT_ALL (E_PAD / 128)  // 782 M-tiles
#define GNODES 32
#define MAXSETS 12
#define NGRP2 313             // ceil(NN / GNODES)
#define NN_PAD (NGRP2 * GNODES)  // 10016

typedef __attribute__((ext_vector_type(8))) short bf16x8;
typedef __attribute__((ext_vector_type(4))) float f32x4;

#define AS1 __attribute__((address_space(1)))
#define AS3 __attribute__((address_space(3)))

__device__ __forceinline__ float bf2f(unsigned short u) {
  union { unsigned int i; float f; } v; v.i = ((unsigned int)u) << 16; return v.f;
}
__device__ __forceinline__ unsigned short f2bf(float f) {
  union { float f; unsigned int i; } v; v.f = f;
  return (unsigned short)((v.i + 0x7FFFu + ((v.i >> 16) & 1u)) >> 16);  // RNE
}

__device__ __forceinline__ void gl_lds16(const void* g, void* lds_base) {
#if __has_builtin(__builtin_amdgcn_global_load_lds)
  __builtin_amdgcn_global_load_lds((const AS1 unsigned int*)g,
                                   (AS3 unsigned int*)lds_base, 16, 0, 0);
#else
  *(uint4*)((char*)lds_base + (threadIdx.x & 63) * 16) = *(const uint4*)g;
#endif
}

// ---------------- weight fp32 -> bf16 transpose: out[n][k] = in[k][n] ----------------
__global__ void convert_transpose_kernel(const float* __restrict__ in,
                                         unsigned short* __restrict__ out,
                                         int K, int N) {
  long long idx = (long long)blockIdx.x * blockDim.x + threadIdx.x;
  if (idx >= (long long)K * N) return;
  int k = (int)(idx % K);
  int n = (int)(idx / K);
  out[idx] = f2bf(in[(long long)k * N + n]);
}

// -------- kp3: k3w repacked into producer MFMA-fragment order ---------------------
// kp3[(((o*32 + rt)*2 + hh)*2 + chalf)*512 + lane*8 + j] =
//   bf16(k3w[r*4096 + c*64 + o]),  r = rt*32 + hh*16 + (lane&15),
//                                  c = chalf*32 + (lane>>4)*8 + j.
__global__ void build_kpt3_kernel(const float* __restrict__ k3w,
                                  unsigned short* __restrict__ kp3) {
  int idx = blockIdx.x * blockDim.x + threadIdx.x;  // 64<<16 = 4,194,304
  if (idx >= (64 << 16)) return;
  int j     = idx & 7;
  int lane  = (idx >> 3) & 63;
  int chalf = (idx >> 9) & 1;
  int hh    = (idx >> 10) & 1;
  int rt    = (idx >> 11) & 31;
  int o     = idx >> 16;
  int r = rt * 32 + hh * 16 + (lane & 15);
  int c = chalf * 32 + (lane >> 4) * 8 + j;
  kp3[idx] = f2bf(k3w[(long long)r * 4096 + c * 64 + o]);
}

// --------- e1 row p (sorted order) = relu(ea[sid[p]] @ k1_w + k1_b), bf16 -----------
// sid == nullptr -> identity (p is the edge id). The 24 B/block ea gather moves the
// src-sort permutation here so the whole downstream chain is contiguous.
__global__ void gemm1_kernel(const float* __restrict__ ea, const float* __restrict__ k1w,
                             const float* __restrict__ k1b, const int* __restrict__ sid,
                             unsigned short* __restrict__ e1c, int e0, int E) {
  int er = blockIdx.x;
  int p = e0 + er;
  int e = (p < E) ? (sid ? sid[p] : p) : -1;
  int t = threadIdx.x * 4;
  float a[6];
#pragma unroll
  for (int j = 0; j < 6; j++) a[j] = (e >= 0) ? ea[(long long)e * 6 + j] : 0.0f;
  float4 b4 = *(const float4*)&k1b[t];
  float acc0 = b4.x, acc1 = b4.y, acc2 = b4.z, acc3 = b4.w;
#pragma unroll
  for (int j = 0; j < 6; j++) {
    float4 w = *(const float4*)&k1w[j * KW + t];
    acc0 += a[j] * w.x; acc1 += a[j] * w.y; acc2 += a[j] * w.z; acc3 += a[j] * w.w;
  }
  ushort4 o;
  o.x = f2bf(fmaxf(acc0, 0.f)); o.y = f2bf(fmaxf(acc1, 0.f));
  o.z = f2bf(fmaxf(acc2, 0.f)); o.w = f2bf(fmaxf(acc3, 0.f));
  *(ushort4*)&e1c[(long long)er * KW + t] = o;
}

// ------- bf16 GEMM: C = A @ BT^T + bias, opt relu ---------------------------------
// kblocked: write C in K-blocked layout C[(n>>5)*E_PAD + (row0+m)][n&31], rows
// contiguous (input already src-sorted) -> fully-sequential 64 B write segments.
__global__ __launch_bounds__(256, 2)
void gemm_bt_kernel(const unsigned short* __restrict__ A,
                    const unsigned short* __restrict__ BT,
                    const float* __restrict__ bias,
                    unsigned short* __restrict__ C,
                    int row0, int N, int K, int mtiles, int do_relu, int kblocked) {
  __shared__ unsigned short sA[128 * 64];
  __shared__ unsigned short sB[128 * 64];
  const int tid  = threadIdx.x;
  const int wave = tid >> 6;
  const int lane = tid & 63;
  const int mt = blockIdx.x % mtiles;
  const int nt = blockIdx.x / mtiles;
  const long long m0 = (long long)mt * 128;
  const int n0 = nt * 128;
  const int wm = wave >> 1, wn = wave & 1;
  const int l15 = lane & 15, quad = lane >> 4;

  f32x4 acc[4][4];
#pragma unroll
  for (int i = 0; i < 4; i++)
#pragma unroll
    for (int j = 0; j < 4; j++) { f32x4 z = {0.f, 0.f, 0.f, 0.f}; acc[i][j] = z; }

  int a_off[4][2], b_off[4][2];
#pragma unroll
  for (int i = 0; i < 4; i++) {
    int ra = wm * 64 + i * 16 + l15;
    int rb = wn * 64 + i * 16 + l15;
#pragma unroll
    for (int kk = 0; kk < 2; kk++) {
      int q = kk * 4 + quad;
      a_off[i][kk] = (ra * 8 + (q ^ (ra & 7))) * 16;
      b_off[i][kk] = (rb * 8 + (q ^ (rb & 7))) * 16;
    }
  }

  int st_row[4], st_q[4];
#pragma unroll
  for (int t = 0; t < 4; t++) {
    int p = (wave * 4 + t) * 64 + lane;
    st_row[t] = p >> 3;
    st_q[t] = (p & 7) ^ ((p >> 3) & 7);
  }

  for (int k0 = 0; k0 < K; k0 += 64) {
    __syncthreads();
#pragma unroll
    for (int t = 0; t < 4; t++) {
      const unsigned short* ga = A + (m0 + st_row[t]) * K + (k0 + st_q[t] * 8);
      const unsigned short* gb = BT + ((long long)(n0 + st_row[t])) * K + (k0 + st_q[t] * 8);
      gl_lds16(ga, (void*)&sA[(wave * 4 + t) * 64 * 8]);
      gl_lds16(gb, (void*)&sB[(wave * 4 + t) * 64 * 8]);
    }
    __syncthreads();

#pragma unroll
    for (int kk = 0; kk < 2; kk++) {
      bf16x8 af[4], bfr[4];
#pragma unroll
      for (int i = 0; i < 4; i++) af[i]  = *(const bf16x8*)((const char*)sA + a_off[i][kk]);
#pragma unroll
      for (int i = 0; i < 4; i++) bfr[i] = *(const bf16x8*)((const char*)sB + b_off[i][kk]);
#pragma unroll
      for (int mi = 0; mi < 4; mi++)
#pragma unroll
        for (int ni = 0; ni < 4; ni++)
          acc[mi][ni] = __builtin_amdgcn_mfma_f32_16x16x32_bf16(af[mi], bfr[ni], acc[mi][ni], 0, 0, 0);
    }
  }

  float bias_v[4];
#pragma unroll
  for (int ni = 0; ni < 4; ni++) bias_v[ni] = bias[n0 + wn * 64 + ni * 16 + l15];
#pragma unroll
  for (int mi = 0; mi < 4; mi++) {
#pragma unroll
    for (int ni = 0; ni < 4; ni++) {
#pragma unroll
      for (int r = 0; r < 4; r++) {
        long long m = m0 + wm * 64 + mi * 16 + quad * 4 + r;
        int n = n0 + wn * 64 + ni * 16 + l15;
        float v = acc[mi][ni][r] + bias_v[ni];
        if (do_relu) v = fmaxf(v, 0.f);
        if (kblocked)
          C[((long long)(n >> 5) * E_PAD + (row0 + m)) * 32 + (n & 31)] = f2bf(v);
        else
          C[m * N + n] = f2bf(v);
      }
    }
  }
}

// ---------------- degree (by dst, fp32) ----------------
__global__ void deg_kernel(const int* __restrict__ dst, float* __restrict__ deg, int E) {
  int e = blockIdx.x * blockDim.x + threadIdx.x;
  if (e < E) atomicAdd(&deg[dst[e]], 1.0f);
}

// ---------------- counting sort (generic by key array) ----------------
__global__ void count_kernel(const int* __restrict__ key, int* __restrict__ cnt, int E) {
  int e = blockIdx.x * blockDim.x + threadIdx.x;
  if (e < E) atomicAdd(&cnt[key[e]], 1);
}

__global__ void scan_kernel(const int* __restrict__ cnt, int* __restrict__ start,
                            int* __restrict__ cursor) {
  __shared__ int psum[1024];
  int t = threadIdx.x;
  int s0 = t * 10;
  int vals[10];
  int local = 0;
#pragma unroll
  for (int i = 0; i < 10; i++) {
    int idx = s0 + i;
    vals[i] = (idx < NN) ? cnt[idx] : 0;
    local += vals[i];
  }
  psum[t] = local;
  __syncthreads();
  for (int off = 1; off < 1024; off <<= 1) {
    int v = (t >= off) ? psum[t - off] : 0;
    __syncthreads();
    psum[t] += v;
    __syncthreads();
  }
  int excl = psum[t] - local;
#pragma unroll
  for (int i = 0; i < 10; i++) {
    int idx = s0 + i;
    if (idx < NN) { start[idx] = excl; cursor[idx] = excl; excl += vals[i]; }
  }
  if (t == 0) start[NN] = NE;
}

// scatter by src; also records pose[e] = src-sorted position of edge e
__global__ void scatter_kernel(const int* __restrict__ src, int* __restrict__ cursor,
                               int* __restrict__ sorted_eid, int* __restrict__ pose, int E) {
  int e = blockIdx.x * blockDim.x + threadIdx.x;
  if (e < E) {
    int pos = atomicAdd(&cursor[src[e]], 1);
    sorted_eid[pos] = e;
    pose[e] = pos;
  }
}

// scatter by dst storing src-sorted positions: dst-CSR of msg rows
__global__ void scatter2_kernel(const int* __restrict__ dst, int* __restrict__ cursor2,
                                const int* __restrict__ pose, int* __restrict__ sid2, int E) {
  int e = blockIdx.x * blockDim.x + threadIdx.x;
  if (e < E) {
    int pos = atomicAdd(&cursor2[dst[e]], 1);
    sid2[pos] = pose[e];
  }
}

// ---------------- per-(group,wave) static tile lists: topology-only, built once -------
__global__ void build_tiles_kernel(const int* __restrict__ start, int2* __restrict__ tiles) {
  int g = blockIdx.x * blockDim.x + threadIdx.x;
  if (g >= NGRP2) return;
  int nt[4] = {0, 0, 0, 0};
  for (int w = 0; w < 4; w++)
    for (int s = 0; s < MAXSETS; s++)
      tiles[(g * 4 + w) * MAXSETS + s] = make_int2(0, 0);
  int t = 0;
  for (int i = 0; i < GNODES; i++) {
    int na = g * GNODES + i;
    int nb = na + 1;
    if (na > NN) na = NN;
    if (nb > NN) nb = NN;
    int s = start[na], e = start[nb];
    for (int m0 = s; m0 < e; m0 += 16) {
      int w = t & 3;
      if (nt[w] < MAXSETS) {
        int c = e - m0; if (c > 16) c = 16;
        tiles[(g * 4 + w) * MAXSETS + nt[w]] = make_int2(i | (c << 16), m0);
        nt[w]++;
      }
      t++;
    }
  }
}

// ---------------- h0 (+ bf16 copy + msg-bias) ----------------
__global__ void h0_mb_kernel(const float* __restrict__ x, const float* __restrict__ fc1w,
                             const float* __restrict__ fc1b, const float* __restrict__ k3b,
                             float* __restrict__ h, unsigned short* __restrict__ hbf,
                             float* __restrict__ mb) {
  int wave = threadIdx.x >> 6, lane = threadIdx.x & 63;
  int n = blockIdx.x * 4 + wave;
  if (n >= NN) return;
  float v = x[n] * fc1w[lane] + fc1b[lane];
  h[n * 64 + lane] = v;
  hbf[n * 64 + lane] = f2bf(v);
  float mbv = 0.f;
#pragma unroll
  for (int c = 0; c < 64; c++)
    mbv += __shfl(v, c, 64) * k3b[c * 64 + lane];
  mb[n * 64 + lane] = mbv;
}

// ---------------- fused per-depth message kernel (d-trick, v11 = v9 + lb4) ----------
// v9 structure (best: 369 us): single 32 KB slab, 2 barriers/rt, e2p prefetch after
// barrier-1 overlapping produce. Coalesced kp3 + e2p (1 KB wave-loads).
// launch_bounds(256,4): VGPR 84 fits, LDS allows 5 blocks -> target 4 blocks/CU.
__global__ __launch_bounds__(256, 4)
void fused_msg_kernel(const unsigned short* __restrict__ hbf,
                      const unsigned short* __restrict__ e2p,
                      const unsigned short* __restrict__ kp3,
                      const int2* __restrict__ tiles,
                      const int* __restrict__ sorted_eid,
                      const int* __restrict__ dst,
                      const float* __restrict__ mb,
                      float* __restrict__ agg,
                      unsigned short* __restrict__ msgh,
                      float* __restrict__ msgf,
                      int msg_mode) {
  __shared__ unsigned short slab[GNODES * 512];  // 32 nodes x 16 o x 32 r = 32 KB
  const int tid = threadIdx.x, wave = tid >> 6, lane = tid & 63;
  const int l15 = lane & 15, quad = lane >> 4;
  const int oh = blockIdx.x & 3;           // XCD-pinned o-quarter
  const int ng = blockIdx.x >> 2;
  const int n0 = ng * GNODES;

  // ---- load static slots ----
  int s_node[MAXSETS], s_j[MAXSETS], s_cnt[MAXSETS], row_off[MAXSETS];
  const int2* tp = tiles + (ng * 4 + wave) * MAXSETS;
#pragma unroll
  for (int s2 = 0; s2 < MAXSETS; s2++) {
    int2 rec = tp[s2];
    s_node[s2] = rec.x & 0xffff;
    s_cnt[s2]  = rec.x >> 16;
    s_j[s2]    = rec.y;
    int c = s_cnt[s2];
    int sl = (l15 < c) ? l15 : (c > 0 ? c - 1 : 0);
    row_off[s2] = (s_j[s2] + sl) * 32 + quad * 8;  // within an rt-slice of e2p
  }

  f32x4 acc[MAXSETS];
#pragma unroll
  for (int s2 = 0; s2 < MAXSETS; s2++) { f32x4 z = {0.f, 0.f, 0.f, 0.f}; acc[s2] = z; }

  // producer B-frags (n = node), two 16-node halves, loop-invariant
  bf16x8 pb0[2], pb1[2];
#pragma unroll
  for (int g2 = 0; g2 < 2; g2++) {
    pb0[g2] = *(const bf16x8*)(hbf + (n0 + g2 * 16 + l15) * 64 + quad * 8);
    pb1[g2] = *(const bf16x8*)(hbf + (n0 + g2 * 16 + l15) * 64 + 32 + quad * 8);
  }

  for (int rt = 0; rt < 32; rt++) {
    __syncthreads();  // WAR: prev consume done before overwrite
    // prefetch consumer e2p frags (coalesced 1 KB wave-loads; overlap produce)
    const unsigned short* e2s = e2p + (size_t)rt * (E_PAD * 32);
    bf16x8 apre[MAXSETS];
#pragma unroll
    for (int s2 = 0; s2 < MAXSETS; s2++) {
      if (s_cnt[s2])  // wave-uniform
        apre[s2] = *(const bf16x8*)(e2s + row_off[s2]);
    }
    // ---- produce: 32 m-tiles (o_loc 16 x hh 2), wave covers 8, coalesced kp3 ----
#pragma unroll 4
    for (int u = 0; u < 8; u++) {
      int id = wave * 8 + u;
      int o_loc = id >> 1, hh = id & 1;
      int o = oh * 16 + o_loc;
      const unsigned short* blk = kp3 + (size_t)(((o * 32 + rt) * 2 + hh) * 2) * 512;
      bf16x8 a0 = *(const bf16x8*)(blk + lane * 8);          // chalf 0
      bf16x8 a1 = *(const bf16x8*)(blk + 512 + lane * 8);    // chalf 1
      int chunk_log = o_loc * 4 + hh * 2 + (quad >> 1);
      int phys = chunk_log ^ (l15 & 7);
#pragma unroll
      for (int g2 = 0; g2 < 2; g2++) {
        f32x4 c = {0.f, 0.f, 0.f, 0.f};
        c = __builtin_amdgcn_mfma_f32_16x16x32_bf16(a0, pb0[g2], c, 0, 0, 0);
        c = __builtin_amdgcn_mfma_f32_16x16x32_bf16(a1, pb1[g2], c, 0, 0, 0);
        // lane: node = g2*16 + l15, r_loc = hh*16 + quad*4 + reg -> one b64
        unsigned int w0 = (unsigned int)f2bf(c[0]) | ((unsigned int)f2bf(c[1]) << 16);
        unsigned int w1 = (unsigned int)f2bf(c[2]) | ((unsigned int)f2bf(c[3]) << 16);
        uint2* p = (uint2*)((char*)slab + (g2 * 16 + l15) * 1024 + phys * 16 + (quad & 1) * 8);
        uint2 w; w.x = w0; w.y = w1;
        *p = w;
      }
    }
    __syncthreads();  // RAW: slab ready
    // ---- consume: static slots, one k=32 MFMA each ----
#pragma unroll
    for (int s2 = 0; s2 < MAXSETS; s2++) {
      if (s_cnt[s2] == 0) continue;  // wave-uniform
      int node = s_node[s2];
      const char* nb = (const char*)slab + node * 1024;
      bf16x8 b = *(const bf16x8*)(nb + (((l15 * 4 + quad) ^ (node & 7)) * 16));
      acc[s2] = __builtin_amdgcn_mfma_f32_16x16x32_bf16(apre[s2], b, acc[s2], 0, 0, 0);
    }
  }

  // ---- epilogue (static slots), o-quarter slice ----
#pragma unroll
  for (int s2 = 0; s2 < MAXSETS; s2++) {
    if (s_cnt[s2] == 0) continue;  // wave-uniform
    float mbv = mb[(n0 + s_node[s2]) * 64 + oh * 16 + l15];
#pragma unroll
    for (int reg = 0; reg < 4; reg++) {
      int mloc = quad * 4 + reg;
      if (mloc < s_cnt[s2]) {
        int p = s_j[s2] + mloc;  // src-sorted position
        float v = acc[s2][reg] + mbv;
        if (msg_mode == 2) {
          __builtin_nontemporal_store(v, &msgf[p * 64 + oh * 16 + l15]);
        } else if (msg_mode == 1) {
          __builtin_nontemporal_store(f2bf(v), &msgh[p * 64 + oh * 16 + l15]);
        } else {
          int d = dst[sorted_eid[p]];
          atomicAdd(&agg[d * 64 + oh * 16 + l15], v);
        }
      }
    }
  }
}

// -------- gather msg rows by dst-CSR + full node update (+hbf/mb for next depth) --------
__global__ void scatter_update_mb_kernel(const unsigned short* __restrict__ msgh,
                                         const float* __restrict__ msgf,
                                         const int* __restrict__ startd,
                                         const int* __restrict__ sid2,
                                         const float* __restrict__ h,
                                         const float* __restrict__ root,
                                         const float* __restrict__ convb,
                                         const float* __restrict__ k3b,
                                         float* __restrict__ hout,
                                         unsigned short* __restrict__ hbf,
                                         float* __restrict__ mb,
                                         int do_relu, int msg_mode) {
  int wave = threadIdx.x >> 6, lane = threadIdx.x & 63;
  int n = blockIdx.x * 4 + wave;
  if (n >= NN) return;
  float hv = h[n * 64 + lane];
  float racc = 0.f;
#pragma unroll
  for (int c = 0; c < 64; c++)
    racc += __shfl(hv, c, 64) * root[c * 64 + lane];
  int js = startd[n], je = startd[n + 1];
  float sum = 0.f;
  if (msg_mode == 2) {
    for (int j = js; j < je; j++) { int p = sid2[j]; sum += msgf[p * 64 + lane]; }
  } else {
    for (int j = js; j < je; j++) { int p = sid2[j]; sum += bf2f(msgh[p * 64 + lane]); }
  }
  float inv = (je > js) ? 1.0f / (float)(je - js) : 0.f;
  float v = sum * inv + racc + convb[lane];
  if (do_relu) v = fmaxf(v, 0.f);
  hout[n * 64 + lane] = v;
  hbf[n * 64 + lane] = f2bf(v);
  float mbv = 0.f;
#pragma unroll
  for (int c = 0; c < 64; c++)
    mbv += __shfl(v, c, 64) * k3b[c * 64 + lane];
  mb[n * 64 + lane] = mbv;
}

// -------- update (+ bf16 copy + msg-bias), atomic-agg variant --------
__global__ void update_mb_kernel(const float* __restrict__ h, const float* __restrict__ agg,
                                 const float* __restrict__ deg, const float* __restrict__ root,
                                 const float* __restrict__ convb, const float* __restrict__ k3b,
                                 float* __restrict__ hout, unsigned short* __restrict__ hbf,
                                 float* __restrict__ mb, int do_relu) {
  int wave = threadIdx.x >> 6, lane = threadIdx.x & 63;
  int n = blockIdx.x * 4 + wave;
  if (n >= NN) return;
  float hv = h[n * 64 + lane];
  float acc = 0.f;
#pragma unroll
  for (int c = 0; c < 64; c++)
    acc += __shfl(hv, c, 64) * root[c * 64 + lane];
  float dg = deg[n];
  float inv = dg > 0.f ? 1.0f / dg : 0.f;
  float v = agg[n * 64 + lane] * inv + acc + convb[lane];
  if (do_relu) v = fmaxf(v, 0.f);
  hout[n * 64 + lane] = v;
  hbf[n * 64 + lane] = f2bf(v);
  float mbv = 0.f;
#pragma unroll
  for (int c = 0; c < 64; c++)
    mbv += __shfl(v, c, 64) * k3b[c * 64 + lane];
  mb[n * 64 + lane] = mbv;
}

// ---------------- fallback-path kernels (round-2 Plan C, proven) ----------------
__global__ void h0_kernel(const float* __restrict__ x, const float* __restrict__ fc1w,
                          const float* __restrict__ fc1b, float* __restrict__ h) {
  int idx = blockIdx.x * blockDim.x + threadIdx.x;
  if (idx >= NN * WIDTH) return;
  int n = idx >> 6, w = idx & 63;
  h[idx] = x[n] * fc1w[w] + fc1b[w];
}

__global__ void msg_kernel(const float* __restrict__ h, const unsigned short* __restrict__ Wc,
                           const int* __restrict__ src, const int* __restrict__ dst,
                           float* __restrict__ agg, int e0, int e_end) {
  int wave = threadIdx.x >> 6;
  int lane = threadIdx.x & 63;
  int e = e0 + blockIdx.x * 4 + wave;
  if (e >= e_end) return;
  int s = src[e], d = dst[e];
  float hv = h[s * WIDTH + lane];
  const unsigned short* We = Wc + (long long)(e - e0) * 4096;
  float acc = 0.f;
#pragma unroll
  for (int c = 0; c < 64; c++) {
    float hs = __shfl(hv, c, 64);
    acc += hs * bf2f(We[c * 64 + lane]);
  }
  atomicAdd(&agg[d * WIDTH + lane], acc);
}

__global__ void update_kernel(const float* __restrict__ h, const float* __restrict__ agg,
                              const float* __restrict__ deg, const float* __restrict__ root,
                              const float* __restrict__ convb, float* __restrict__ hout,
                              int do_relu) {
  int wave = threadIdx.x >> 6, lane = threadIdx.x & 63;
  int n = blockIdx.x * 4 + wave;
  if (n >= NN) return;
  float hv = h[n * WIDTH + lane];
  float acc = 0.f;
#pragma unroll
  for (int c = 0; c < 64; c++)
    acc += __shfl(hv, c, 64) * root[c * WIDTH + lane];
  float dg = deg[n];
  float inv = dg > 0.f ? 1.0f / dg : 0.f;
  float v = agg[n * WIDTH + lane] * inv + acc + convb[lane];
  if (do_relu) v = fmaxf(v, 0.f);
  hout[n * WIDTH + lane] = v;
}

__global__ void fc2_kernel(const float* __restrict__ h, const float* __restrict__ fc2w,
                           const float* __restrict__ fc2b, float* __restrict__ out) {
  int wave = threadIdx.x >> 6, lane = threadIdx.x & 63;
  int n = blockIdx.x * 4 + wave;
  if (n >= NN) return;
  float v = h[n * WIDTH + lane] * fc2w[lane];
#pragma unroll
  for (int off = 32; off > 0; off >>= 1) v += __shfl_down(v, off, 64);
  if (lane == 0) out[n] = v + fc2b[0];
}

extern "C" void kernel_launch(void* const* d_in, const int* in_sizes, int n_in,
                              void* d_out, int out_size, void* d_ws, size_t ws_size,
                              hipStream_t stream) {
  const float* x     = (const float*)d_in[0];
  const int*   ei    = (const int*)d_in[1];
  const float* ea    = (const float*)d_in[2];
  const float* fc1w  = (const float*)d_in[3];
  const float* fc1b  = (const float*)d_in[4];
  const float* k1w   = (const float*)d_in[5];
  const float* k1b   = (const float*)d_in[6];
  const float* k2w   = (const float*)d_in[7];
  const float* k2b   = (const float*)d_in[8];
  const float* k3w   = (const float*)d_in[9];
  const float* k3b   = (const float*)d_in[10];
  const float* root  = (const float*)d_in[11];
  const float* convb = (const float*)d_in[12];
  const float* fc2w  = (const float*)d_in[13];
  const float* fc2b  = (const float*)d_in[14];
  float* out = (float*)d_out;
  const int* src = ei;
  const int* dst = ei + NE;

  char* ws = (char*)d_ws;
  size_t off = 0;
  auto alloc = [&](size_t bytes) -> char* {
    char* p = ws + off; off = (off + bytes + 255) & ~(size_t)255; return p;
  };
  auto al = [](size_t x) { return (x + 255) & ~(size_t)255; };

  // ---- common ----
  unsigned short* k2wT = (unsigned short*)alloc((size_t)KW * KW * 2);
  float* ha  = (float*)alloc((size_t)NN * WIDTH * 4);
  float* hb  = (float*)alloc((size_t)NN * WIDTH * 4);
  float* agg = (float*)alloc((size_t)NN * WIDTH * 4);
  float* deg = (float*)alloc((size_t)NN * 4);
  if (ws_size < off + 4096) return;

  const size_t PT_CH = 128 * KW * 2;  // 262144

  size_t sz_kpt  = (size_t)(64 << 16) * 2;     // kp3: 8.39 MB
  size_t sz_mb   = (size_t)NN * 64 * 4;
  size_t sz_hbf  = (size_t)NN_PAD * 64 * 2;
  size_t sz_cnt  = (size_t)NN * 4;
  size_t sz_st   = (size_t)(NN + 1) * 4;
  size_t sz_sid  = (size_t)NE * 4;
  size_t sz_e2   = (size_t)E_PAD * KW * 2;     // e2p
  size_t sz_tiles = (size_t)NGRP2 * 4 * MAXSETS * 8;

  size_t core = al(sz_kpt) + al(sz_mb) + al(sz_hbf) + al(sz_cnt) + al(sz_st) + al(sz_cnt)
              + al(sz_sid) + al(sz_e2) + al(sz_tiles) + al(sz_sid) /*pose*/;
  size_t msg_csr = al(sz_cnt) + al(sz_st) + al(sz_cnt) + al(sz_sid);
  size_t e1c_min = al((size_t)8 * PT_CH);

  int msg_mode;  // 2 = fp32 msg buffer, 1 = bf16 msg buffer, 0 = atomic agg, -1 = Plan C
  if (ws_size >= off + core + msg_csr + al((size_t)NE * 64 * 4) + e1c_min)       msg_mode = 2;
  else if (ws_size >= off + core + msg_csr + al((size_t)NE * 64 * 2) + e1c_min)  msg_mode = 1;
  else if (ws_size >= off + core + e1c_min + 8192)                               msg_mode = 0;
  else                                                                           msg_mode = -1;

  if (msg_mode >= 0) {
    // ================= FUSED d-TRICK PATH (v11) =================
    unsigned short* kp3 = (unsigned short*)alloc(sz_kpt);
    float* mb   = (float*)alloc(sz_mb);
    unsigned short* hbf = (unsigned short*)alloc(sz_hbf);
    int* cnt    = (int*)alloc(sz_cnt);
    int* starta = (int*)alloc(sz_st);
    int* cursor = (int*)alloc(sz_cnt);
    int* sid    = (int*)alloc(sz_sid);
    unsigned short* e2p = (unsigned short*)alloc(sz_e2);
    int2* tiles = (int2*)alloc(sz_tiles);
    int* pose   = (int*)alloc(sz_sid);
    int* cnt2 = nullptr; int* startd = nullptr;
    int* cursor2 = nullptr; int* sid2 = nullptr;
    unsigned short* msgh = nullptr; float* msgf = nullptr;
    if (msg_mode >= 1) {
      cnt2    = (int*)alloc(sz_cnt);
      startd  = (int*)alloc(sz_st);
      cursor2 = (int*)alloc(sz_cnt);
      sid2    = (int*)alloc(sz_sid);
      if (msg_mode == 2) msgf = (float*)alloc((size_t)NE * 64 * 4);
      else               msgh = (unsigned short*)alloc((size_t)NE * 64 * 2);
    }
    size_t left = ws_size - off;
    int TC = (int)(left / PT_CH); if (TC > 98) TC = 98;
    unsigned short* e1c = (unsigned short*)alloc((size_t)TC * PT_CH);

    convert_transpose_kernel<<<(KW * KW) / 256, 256, 0, stream>>>(k2w, k2wT, KW, KW);
    build_kpt3_kernel<<<(64 << 16) / 256, 256, 0, stream>>>(k3w, kp3);
    hipMemsetAsync(cnt, 0, sz_cnt, stream);
    count_kernel<<<(NE + 255) / 256, 256, 0, stream>>>(src, cnt, NE);
    scan_kernel<<<1, 1024, 0, stream>>>(cnt, starta, cursor);
    scatter_kernel<<<(NE + 255) / 256, 256, 0, stream>>>(src, cursor, sid, pose, NE);
    build_tiles_kernel<<<(NGRP2 + 255) / 256, 256, 0, stream>>>(starta, tiles);
    if (msg_mode >= 1) {
      hipMemsetAsync(cnt2, 0, sz_cnt, stream);
      count_kernel<<<(NE + 255) / 256, 256, 0, stream>>>(dst, cnt2, NE);
      scan_kernel<<<1, 1024, 0, stream>>>(cnt2, startd, cursor2);
      scatter2_kernel<<<(NE + 255) / 256, 256, 0, stream>>>(dst, cursor2, pose, sid2, NE);
    } else {
      hipMemsetAsync(deg, 0, (size_t)NN * 4, stream);
      deg_kernel<<<(NE + 255) / 256, 256, 0, stream>>>(dst, deg, NE);
    }
    h0_mb_kernel<<<(NN + 3) / 4, 256, 0, stream>>>(x, fc1w, fc1b, k3b, ha, hbf, mb);
    // e1 gathered via sid (sorted order) -> gemm2 writes e2p contiguously
    for (int t0 = 0; t0 < MT_ALL; t0 += TC) {
      int tc = (MT_ALL - t0 < TC) ? (MT_ALL - t0) : TC;
      gemm1_kernel<<<tc * 128, 256, 0, stream>>>(ea, k1w, k1b, sid, e1c, t0 * 128, NE);
      gemm_bt_kernel<<<tc * (KW / 128), 256, 0, stream>>>(
          e1c, k2wT, k2b, e2p, t0 * 128, KW, KW, tc, 1, 1);
    }
    float* hc = ha; float* hn = hb;
    for (int k = 0; k < DEPTH; k++) {
      if (msg_mode == 0) hipMemsetAsync(agg, 0, (size_t)NN * WIDTH * 4, stream);
      fused_msg_kernel<<<4 * NGRP2, 256, 0, stream>>>(
          hbf, e2p, kp3, tiles, sid, dst, mb, agg, msgh, msgf, msg_mode);
      if (msg_mode >= 1)
        scatter_update_mb_kernel<<<(NN + 3) / 4, 256, 0, stream>>>(
            msgh, msgf, startd, sid2, hc, root, convb, k3b, hn, hbf, mb,
            (k != DEPTH - 1) ? 1 : 0, msg_mode);
      else
        update_mb_kernel<<<(NN + 3) / 4, 256, 0, stream>>>(
            hc, agg, deg, root, convb, k3b, hn, hbf, mb, (k != DEPTH - 1) ? 1 : 0);
      float* t = hc; hc = hn; hn = t;
    }
    fc2_kernel<<<(NN + 3) / 4, 256, 0, stream>>>(hc, fc2w, fc2b, out);
  } else {
    // ================= FALLBACK: round-2 Plan C (proven) =================
    unsigned short* k3wT = (unsigned short*)alloc((size_t)4096 * KW * 2);
    size_t rem = (ws_size > off) ? ws_size - off : 0;
    const size_t PT_W = 128 * 4096 * 2;
    size_t per_tile = 2 * PT_CH + PT_W;
    long long tcl = (long long)(rem / per_tile);
    int TC = (tcl > 98) ? 98 : (int)tcl;
    if (TC < 1) return;
    unsigned short* e1c = (unsigned short*)alloc((size_t)TC * PT_CH);
    unsigned short* e2c = (unsigned short*)alloc((size_t)TC * PT_CH);
    unsigned short* Wc  = (unsigned short*)alloc((size_t)TC * PT_W);

    convert_transpose_kernel<<<(KW * KW) / 256, 256, 0, stream>>>(k2w, k2wT, KW, KW);
    convert_transpose_kernel<<<(KW * 4096) / 256, 256, 0, stream>>>(k3w, k3wT, KW, 4096);
    hipMemsetAsync(deg, 0, (size_t)NN * 4, stream);
    deg_kernel<<<(NE + 255) / 256, 256, 0, stream>>>(dst, deg, NE);
    h0_kernel<<<(NN * WIDTH) / 256, 256, 0, stream>>>(x, fc1w, fc1b, ha);

    float* hc = ha; float* hn = hb;
    for (int k = 0; k < DEPTH; k++) {
      hipMemsetAsync(agg, 0, (size_t)NN * WIDTH * 4, stream);
      for (int t0 = 0; t0 < MT_ALL; t0 += TC) {
        int tc = (MT_ALL - t0 < TC) ? (MT_ALL - t0) : TC;
        gemm1_kernel<<<tc * 128, 256, 0, stream>>>(ea, k1w, k1b, nullptr, e1c, t0 * 128, NE);
        gemm_bt_kernel<<<tc * (KW / 128), 256, 0, stream>>>(e1c, k2wT, k2b, e2c,
                                                            0, KW, KW, tc, 1, 0);
        gemm_bt_kernel<<<tc * (4096 / 128), 256, 0, stream>>>(e2c, k3wT, k3b, Wc,
                                                              0, 4096, KW, tc, 0, 0);
        int e0 = t0 * 128;
        int e_end = (t0 + tc) * 128; if (e_end > NE) e_end = NE;
        if (e_end > e0)
          msg_kernel<<<(e_end - e0 + 3) / 4, 256, 0, stream>>>(hc, Wc, src, dst, agg, e0, e_end);
      }
      update_kernel<<<(NN + 3) / 4, 256, 0, stream>>>(hc, agg, deg, root, convb, hn,
                                                      (k != DEPTH - 1) ? 1 : 0);
      float* t = hc; hc = hn; hn = t;
    }
    fc2_kernel<<<(NN + 3) / 4, 256, 0, stream>>>(hc, fc2w, fc2b, out);
  }
}

// Round 14
// 4082.856 us; speedup vs baseline: 1.5009x; 1.5009x over previous
//
#include <hip/hip_runtime.h>
#include <hip/hip_bf16.h>

#define WIDTH 64
#define KW 1024
#define DEPTH 6
#define NN 10000
#define NE 100000
#define E_PAD 100096          // 782 * 128
#define MT_ALL (E_PAD / 128)  // 782 M-tiles
#define GNODES 32
#define MAXSETS 12
#define NGRP2 313             // ceil(NN / GNODES)
#define NN_PAD (NGRP2 * GNODES)  // 10016

typedef __attribute__((ext_vector_type(8))) short bf16x8;
typedef __attribute__((ext_vector_type(4))) float f32x4;

#define AS1 __attribute__((address_space(1)))
#define AS3 __attribute__((address_space(3)))

__device__ __forceinline__ float bf2f(unsigned short u) {
  union { unsigned int i; float f; } v; v.i = ((unsigned int)u) << 16; return v.f;
}
__device__ __forceinline__ unsigned short f2bf(float f) {
  union { float f; unsigned int i; } v; v.f = f;
  return (unsigned short)((v.i + 0x7FFFu + ((v.i >> 16) & 1u)) >> 16);  // RNE
}

__device__ __forceinline__ void gl_lds16(const void* g, void* lds_base) {
#if __has_builtin(__builtin_amdgcn_global_load_lds)
  __builtin_amdgcn_global_load_lds((const AS1 unsigned int*)g,
                                   (AS3 unsigned int*)lds_base, 16, 0, 0);
#else
  *(uint4*)((char*)lds_base + (threadIdx.x & 63) * 16) = *(const uint4*)g;
#endif
}

// ---------------- weight fp32 -> bf16 transpose: out[n][k] = in[k][n] ----------------
__global__ void convert_transpose_kernel(const float* __restrict__ in,
                                         unsigned short* __restrict__ out,
                                         int K, int N) {
  long long idx = (long long)blockIdx.x * blockDim.x + threadIdx.x;
  if (idx >= (long long)K * N) return;
  int k = (int)(idx % K);
  int n = (int)(idx / K);
  out[idx] = f2bf(in[(long long)k * N + n]);
}

// -------- kp3: k3w repacked into producer MFMA-fragment order ---------------------
// kp3[(((o*32 + rt)*2 + hh)*2 + chalf)*512 + lane*8 + j] =
//   bf16(k3w[r*4096 + c*64 + o]),  r = rt*32 + hh*16 + (lane&15),
//                                  c = chalf*32 + (lane>>4)*8 + j.
__global__ void build_kpt3_kernel(const float* __restrict__ k3w,
                                  unsigned short* __restrict__ kp3) {
  int idx = blockIdx.x * blockDim.x + threadIdx.x;  // 64<<16 = 4,194,304
  if (idx >= (64 << 16)) return;
  int j     = idx & 7;
  int lane  = (idx >> 3) & 63;
  int chalf = (idx >> 9) & 1;
  int hh    = (idx >> 10) & 1;
  int rt    = (idx >> 11) & 31;
  int o     = idx >> 16;
  int r = rt * 32 + hh * 16 + (lane & 15);
  int c = chalf * 32 + (lane >> 4) * 8 + j;
  kp3[idx] = f2bf(k3w[(long long)r * 4096 + c * 64 + o]);
}

// --------- e1 row p (sorted order) = relu(ea[sid[p]] @ k1_w + k1_b), bf16 -----------
__global__ void gemm1_kernel(const float* __restrict__ ea, const float* __restrict__ k1w,
                             const float* __restrict__ k1b, const int* __restrict__ sid,
                             unsigned short* __restrict__ e1c, int e0, int E) {
  int er = blockIdx.x;
  int p = e0 + er;
  int e = (p < E) ? (sid ? sid[p] : p) : -1;
  int t = threadIdx.x * 4;
  float a[6];
#pragma unroll
  for (int j = 0; j < 6; j++) a[j] = (e >= 0) ? ea[(long long)e * 6 + j] : 0.0f;
  float4 b4 = *(const float4*)&k1b[t];
  float acc0 = b4.x, acc1 = b4.y, acc2 = b4.z, acc3 = b4.w;
#pragma unroll
  for (int j = 0; j < 6; j++) {
    float4 w = *(const float4*)&k1w[j * KW + t];
    acc0 += a[j] * w.x; acc1 += a[j] * w.y; acc2 += a[j] * w.z; acc3 += a[j] * w.w;
  }
  ushort4 o;
  o.x = f2bf(fmaxf(acc0, 0.f)); o.y = f2bf(fmaxf(acc1, 0.f));
  o.z = f2bf(fmaxf(acc2, 0.f)); o.w = f2bf(fmaxf(acc3, 0.f));
  *(ushort4*)&e1c[(long long)er * KW + t] = o;
}

// ------- bf16 GEMM: C = A @ BT^T + bias, opt relu ---------------------------------
// kblocked: write C in K-blocked layout C[(n>>5)*E_PAD + (row0+m)][n&31], rows
// contiguous (input already src-sorted).
__global__ __launch_bounds__(256, 2)
void gemm_bt_kernel(const unsigned short* __restrict__ A,
                    const unsigned short* __restrict__ BT,
                    const float* __restrict__ bias,
                    unsigned short* __restrict__ C,
                    int row0, int N, int K, int mtiles, int do_relu, int kblocked) {
  __shared__ unsigned short sA[128 * 64];
  __shared__ unsigned short sB[128 * 64];
  const int tid  = threadIdx.x;
  const int wave = tid >> 6;
  const int lane = tid & 63;
  const int mt = blockIdx.x % mtiles;
  const int nt = blockIdx.x / mtiles;
  const long long m0 = (long long)mt * 128;
  const int n0 = nt * 128;
  const int wm = wave >> 1, wn = wave & 1;
  const int l15 = lane & 15, quad = lane >> 4;

  f32x4 acc[4][4];
#pragma unroll
  for (int i = 0; i < 4; i++)
#pragma unroll
    for (int j = 0; j < 4; j++) { f32x4 z = {0.f, 0.f, 0.f, 0.f}; acc[i][j] = z; }

  int a_off[4][2], b_off[4][2];
#pragma unroll
  for (int i = 0; i < 4; i++) {
    int ra = wm * 64 + i * 16 + l15;
    int rb = wn * 64 + i * 16 + l15;
#pragma unroll
    for (int kk = 0; kk < 2; kk++) {
      int q = kk * 4 + quad;
      a_off[i][kk] = (ra * 8 + (q ^ (ra & 7))) * 16;
      b_off[i][kk] = (rb * 8 + (q ^ (rb & 7))) * 16;
    }
  }

  int st_row[4], st_q[4];
#pragma unroll
  for (int t = 0; t < 4; t++) {
    int p = (wave * 4 + t) * 64 + lane;
    st_row[t] = p >> 3;
    st_q[t] = (p & 7) ^ ((p >> 3) & 7);
  }

  for (int k0 = 0; k0 < K; k0 += 64) {
    __syncthreads();
#pragma unroll
    for (int t = 0; t < 4; t++) {
      const unsigned short* ga = A + (m0 + st_row[t]) * K + (k0 + st_q[t] * 8);
      const unsigned short* gb = BT + ((long long)(n0 + st_row[t])) * K + (k0 + st_q[t] * 8);
      gl_lds16(ga, (void*)&sA[(wave * 4 + t) * 64 * 8]);
      gl_lds16(gb, (void*)&sB[(wave * 4 + t) * 64 * 8]);
    }
    __syncthreads();

#pragma unroll
    for (int kk = 0; kk < 2; kk++) {
      bf16x8 af[4], bfr[4];
#pragma unroll
      for (int i = 0; i < 4; i++) af[i]  = *(const bf16x8*)((const char*)sA + a_off[i][kk]);
#pragma unroll
      for (int i = 0; i < 4; i++) bfr[i] = *(const bf16x8*)((const char*)sB + b_off[i][kk]);
#pragma unroll
      for (int mi = 0; mi < 4; mi++)
#pragma unroll
        for (int ni = 0; ni < 4; ni++)
          acc[mi][ni] = __builtin_amdgcn_mfma_f32_16x16x32_bf16(af[mi], bfr[ni], acc[mi][ni], 0, 0, 0);
    }
  }

  float bias_v[4];
#pragma unroll
  for (int ni = 0; ni < 4; ni++) bias_v[ni] = bias[n0 + wn * 64 + ni * 16 + l15];
#pragma unroll
  for (int mi = 0; mi < 4; mi++) {
#pragma unroll
    for (int ni = 0; ni < 4; ni++) {
#pragma unroll
      for (int r = 0; r < 4; r++) {
        long long m = m0 + wm * 64 + mi * 16 + quad * 4 + r;
        int n = n0 + wn * 64 + ni * 16 + l15;
        float v = acc[mi][ni][r] + bias_v[ni];
        if (do_relu) v = fmaxf(v, 0.f);
        if (kblocked)
          C[((long long)(n >> 5) * E_PAD + (row0 + m)) * 32 + (n & 31)] = f2bf(v);
        else
          C[m * N + n] = f2bf(v);
      }
    }
  }
}

// ---------------- degree (by dst, fp32) ----------------
__global__ void deg_kernel(const int* __restrict__ dst, float* __restrict__ deg, int E) {
  int e = blockIdx.x * blockDim.x + threadIdx.x;
  if (e < E) atomicAdd(&deg[dst[e]], 1.0f);
}

// ---------------- counting sort (generic by key array) ----------------
__global__ void count_kernel(const int* __restrict__ key, int* __restrict__ cnt, int E) {
  int e = blockIdx.x * blockDim.x + threadIdx.x;
  if (e < E) atomicAdd(&cnt[key[e]], 1);
}

__global__ void scan_kernel(const int* __restrict__ cnt, int* __restrict__ start,
                            int* __restrict__ cursor) {
  __shared__ int psum[1024];
  int t = threadIdx.x;
  int s0 = t * 10;
  int vals[10];
  int local = 0;
#pragma unroll
  for (int i = 0; i < 10; i++) {
    int idx = s0 + i;
    vals[i] = (idx < NN) ? cnt[idx] : 0;
    local += vals[i];
  }
  psum[t] = local;
  __syncthreads();
  for (int off = 1; off < 1024; off <<= 1) {
    int v = (t >= off) ? psum[t - off] : 0;
    __syncthreads();
    psum[t] += v;
    __syncthreads();
  }
  int excl = psum[t] - local;
#pragma unroll
  for (int i = 0; i < 10; i++) {
    int idx = s0 + i;
    if (idx < NN) { start[idx] = excl; cursor[idx] = excl; excl += vals[i]; }
  }
  if (t == 0) start[NN] = NE;
}

// scatter by src; also records pose[e] = src-sorted position of edge e
__global__ void scatter_kernel(const int* __restrict__ src, int* __restrict__ cursor,
                               int* __restrict__ sorted_eid, int* __restrict__ pose, int E) {
  int e = blockIdx.x * blockDim.x + threadIdx.x;
  if (e < E) {
    int pos = atomicAdd(&cursor[src[e]], 1);
    sorted_eid[pos] = e;
    pose[e] = pos;
  }
}

// scatter by dst storing src-sorted positions: dst-CSR of msg rows
__global__ void scatter2_kernel(const int* __restrict__ dst, int* __restrict__ cursor2,
                                const int* __restrict__ pose, int* __restrict__ sid2, int E) {
  int e = blockIdx.x * blockDim.x + threadIdx.x;
  if (e < E) {
    int pos = atomicAdd(&cursor2[dst[e]], 1);
    sid2[pos] = pose[e];
  }
}

// ---------------- per-(group,wave) static tile lists: topology-only, built once -------
__global__ void build_tiles_kernel(const int* __restrict__ start, int2* __restrict__ tiles) {
  int g = blockIdx.x * blockDim.x + threadIdx.x;
  if (g >= NGRP2) return;
  int nt[4] = {0, 0, 0, 0};
  for (int w = 0; w < 4; w++)
    for (int s = 0; s < MAXSETS; s++)
      tiles[(g * 4 + w) * MAXSETS + s] = make_int2(0, 0);
  int t = 0;
  for (int i = 0; i < GNODES; i++) {
    int na = g * GNODES + i;
    int nb = na + 1;
    if (na > NN) na = NN;
    if (nb > NN) nb = NN;
    int s = start[na], e = start[nb];
    for (int m0 = s; m0 < e; m0 += 16) {
      int w = t & 3;
      if (nt[w] < MAXSETS) {
        int c = e - m0; if (c > 16) c = 16;
        tiles[(g * 4 + w) * MAXSETS + nt[w]] = make_int2(i | (c << 16), m0);
        nt[w]++;
      }
      t++;
    }
  }
}

// ---------------- h0 (+ bf16 copy + msg-bias) ----------------
__global__ void h0_mb_kernel(const float* __restrict__ x, const float* __restrict__ fc1w,
                             const float* __restrict__ fc1b, const float* __restrict__ k3b,
                             float* __restrict__ h, unsigned short* __restrict__ hbf,
                             float* __restrict__ mb) {
  int wave = threadIdx.x >> 6, lane = threadIdx.x & 63;
  int n = blockIdx.x * 4 + wave;
  if (n >= NN) return;
  float v = x[n] * fc1w[lane] + fc1b[lane];
  h[n * 64 + lane] = v;
  hbf[n * 64 + lane] = f2bf(v);
  float mbv = 0.f;
#pragma unroll
  for (int c = 0; c < 64; c++)
    mbv += __shfl(v, c, 64) * k3b[c * 64 + lane];
  mb[n * 64 + lane] = mbv;
}

// ---------------- fused per-depth message kernel (d-trick, v12 = exact v9) ----------
// v9 structure (best measured: 369 us): single 32 KB slab, 2 barriers/rt, e2p
// prefetch after barrier-1 overlapping produce; coalesced kp3 + e2p 1 KB wave-loads.
// launch_bounds(256,3): 84 VGPR, NO SPILLS. (256,4) forces the 64-VGPR step and
// spills apre/acc to scratch (+500 MB WRITE, 2x dur) — measured round 13.
__global__ __launch_bounds__(256, 3)
void fused_msg_kernel(const unsigned short* __restrict__ hbf,
                      const unsigned short* __restrict__ e2p,
                      const unsigned short* __restrict__ kp3,
                      const int2* __restrict__ tiles,
                      const int* __restrict__ sorted_eid,
                      const int* __restrict__ dst,
                      const float* __restrict__ mb,
                      float* __restrict__ agg,
                      unsigned short* __restrict__ msgh,
                      float* __restrict__ msgf,
                      int msg_mode) {
  __shared__ unsigned short slab[GNODES * 512];  // 32 nodes x 16 o x 32 r = 32 KB
  const int tid = threadIdx.x, wave = tid >> 6, lane = tid & 63;
  const int l15 = lane & 15, quad = lane >> 4;
  const int oh = blockIdx.x & 3;           // XCD-pinned o-quarter
  const int ng = blockIdx.x >> 2;
  const int n0 = ng * GNODES;

  // ---- load static slots ----
  int s_node[MAXSETS], s_j[MAXSETS], s_cnt[MAXSETS], row_off[MAXSETS];
  const int2* tp = tiles + (ng * 4 + wave) * MAXSETS;
#pragma unroll
  for (int s2 = 0; s2 < MAXSETS; s2++) {
    int2 rec = tp[s2];
    s_node[s2] = rec.x & 0xffff;
    s_cnt[s2]  = rec.x >> 16;
    s_j[s2]    = rec.y;
    int c = s_cnt[s2];
    int sl = (l15 < c) ? l15 : (c > 0 ? c - 1 : 0);
    row_off[s2] = (s_j[s2] + sl) * 32 + quad * 8;  // within an rt-slice of e2p
  }

  f32x4 acc[MAXSETS];
#pragma unroll
  for (int s2 = 0; s2 < MAXSETS; s2++) { f32x4 z = {0.f, 0.f, 0.f, 0.f}; acc[s2] = z; }

  // producer B-frags (n = node), two 16-node halves, loop-invariant
  bf16x8 pb0[2], pb1[2];
#pragma unroll
  for (int g2 = 0; g2 < 2; g2++) {
    pb0[g2] = *(const bf16x8*)(hbf + (n0 + g2 * 16 + l15) * 64 + quad * 8);
    pb1[g2] = *(const bf16x8*)(hbf + (n0 + g2 * 16 + l15) * 64 + 32 + quad * 8);
  }

  for (int rt = 0; rt < 32; rt++) {
    __syncthreads();  // WAR: prev consume done before overwrite
    // prefetch consumer e2p frags (coalesced 1 KB wave-loads; overlap produce)
    const unsigned short* e2s = e2p + (size_t)rt * (E_PAD * 32);
    bf16x8 apre[MAXSETS];
#pragma unroll
    for (int s2 = 0; s2 < MAXSETS; s2++) {
      if (s_cnt[s2])  // wave-uniform
        apre[s2] = *(const bf16x8*)(e2s + row_off[s2]);
    }
    // ---- produce: 32 m-tiles (o_loc 16 x hh 2), wave covers 8, coalesced kp3 ----
#pragma unroll 4
    for (int u = 0; u < 8; u++) {
      int id = wave * 8 + u;
      int o_loc = id >> 1, hh = id & 1;
      int o = oh * 16 + o_loc;
      const unsigned short* blk = kp3 + (size_t)(((o * 32 + rt) * 2 + hh) * 2) * 512;
      bf16x8 a0 = *(const bf16x8*)(blk + lane * 8);          // chalf 0
      bf16x8 a1 = *(const bf16x8*)(blk + 512 + lane * 8);    // chalf 1
      int chunk_log = o_loc * 4 + hh * 2 + (quad >> 1);
      int phys = chunk_log ^ (l15 & 7);
#pragma unroll
      for (int g2 = 0; g2 < 2; g2++) {
        f32x4 c = {0.f, 0.f, 0.f, 0.f};
        c = __builtin_amdgcn_mfma_f32_16x16x32_bf16(a0, pb0[g2], c, 0, 0, 0);
        c = __builtin_amdgcn_mfma_f32_16x16x32_bf16(a1, pb1[g2], c, 0, 0, 0);
        // lane: node = g2*16 + l15, r_loc = hh*16 + quad*4 + reg -> one b64
        unsigned int w0 = (unsigned int)f2bf(c[0]) | ((unsigned int)f2bf(c[1]) << 16);
        unsigned int w1 = (unsigned int)f2bf(c[2]) | ((unsigned int)f2bf(c[3]) << 16);
        uint2* p = (uint2*)((char*)slab + (g2 * 16 + l15) * 1024 + phys * 16 + (quad & 1) * 8);
        uint2 w; w.x = w0; w.y = w1;
        *p = w;
      }
    }
    __syncthreads();  // RAW: slab ready
    // ---- consume: static slots, one k=32 MFMA each ----
#pragma unroll
    for (int s2 = 0; s2 < MAXSETS; s2++) {
      if (s_cnt[s2] == 0) continue;  // wave-uniform
      int node = s_node[s2];
      const char* nb = (const char*)slab + node * 1024;
      bf16x8 b = *(const bf16x8*)(nb + (((l15 * 4 + quad) ^ (node & 7)) * 16));
      acc[s2] = __builtin_amdgcn_mfma_f32_16x16x32_bf16(apre[s2], b, acc[s2], 0, 0, 0);
    }
  }

  // ---- epilogue (static slots), o-quarter slice ----
#pragma unroll
  for (int s2 = 0; s2 < MAXSETS; s2++) {
    if (s_cnt[s2] == 0) continue;  // wave-uniform
    float mbv = mb[(n0 + s_node[s2]) * 64 + oh * 16 + l15];
#pragma unroll
    for (int reg = 0; reg < 4; reg++) {
      int mloc = quad * 4 + reg;
      if (mloc < s_cnt[s2]) {
        int p = s_j[s2] + mloc;  // src-sorted position
        float v = acc[s2][reg] + mbv;
        if (msg_mode == 2) {
          __builtin_nontemporal_store(v, &msgf[p * 64 + oh * 16 + l15]);
        } else if (msg_mode == 1) {
          __builtin_nontemporal_store(f2bf(v), &msgh[p * 64 + oh * 16 + l15]);
        } else {
          int d = dst[sorted_eid[p]];
          atomicAdd(&agg[d * 64 + oh * 16 + l15], v);
        }
      }
    }
  }
}

// -------- gather msg rows by dst-CSR + full node update (+hbf/mb for next depth) --------
__global__ void scatter_update_mb_kernel(const unsigned short* __restrict__ msgh,
                                         const float* __restrict__ msgf,
                                         const int* __restrict__ startd,
                                         const int* __restrict__ sid2,
                                         const float* __restrict__ h,
                                         const float* __restrict__ root,
                                         const float* __restrict__ convb,
                                         const float* __restrict__ k3b,
                                         float* __restrict__ hout,
                                         unsigned short* __restrict__ hbf,
                                         float* __restrict__ mb,
                                         int do_relu, int msg_mode) {
  int wave = threadIdx.x >> 6, lane = threadIdx.x & 63;
  int n = blockIdx.x * 4 + wave;
  if (n >= NN) return;
  float hv = h[n * 64 + lane];
  float racc = 0.f;
#pragma unroll
  for (int c = 0; c < 64; c++)
    racc += __shfl(hv, c, 64) * root[c * 64 + lane];
  int js = startd[n], je = startd[n + 1];
  float sum = 0.f;
  if (msg_mode == 2) {
    for (int j = js; j < je; j++) { int p = sid2[j]; sum += msgf[p * 64 + lane]; }
  } else {
    for (int j = js; j < je; j++) { int p = sid2[j]; sum += bf2f(msgh[p * 64 + lane]); }
  }
  float inv = (je > js) ? 1.0f / (float)(je - js) : 0.f;
  float v = sum * inv + racc + convb[lane];
  if (do_relu) v = fmaxf(v, 0.f);
  hout[n * 64 + lane] = v;
  hbf[n * 64 + lane] = f2bf(v);
  float mbv = 0.f;
#pragma unroll
  for (int c = 0; c < 64; c++)
    mbv += __shfl(v, c, 64) * k3b[c * 64 + lane];
  mb[n * 64 + lane] = mbv;
}

// -------- update (+ bf16 copy + msg-bias), atomic-agg variant --------
__global__ void update_mb_kernel(const float* __restrict__ h, const float* __restrict__ agg,
                                 const float* __restrict__ deg, const float* __restrict__ root,
                                 const float* __restrict__ convb, const float* __restrict__ k3b,
                                 float* __restrict__ hout, unsigned short* __restrict__ hbf,
                                 float* __restrict__ mb, int do_relu) {
  int wave = threadIdx.x >> 6, lane = threadIdx.x & 63;
  int n = blockIdx.x * 4 + wave;
  if (n >= NN) return;
  float hv = h[n * 64 + lane];
  float acc = 0.f;
#pragma unroll
  for (int c = 0; c < 64; c++)
    acc += __shfl(hv, c, 64) * root[c * 64 + lane];
  float dg = deg[n];
  float inv = dg > 0.f ? 1.0f / dg : 0.f;
  float v = agg[n * 64 + lane] * inv + acc + convb[lane];
  if (do_relu) v = fmaxf(v, 0.f);
  hout[n * 64 + lane] = v;
  hbf[n * 64 + lane] = f2bf(v);
  float mbv = 0.f;
#pragma unroll
  for (int c = 0; c < 64; c++)
    mbv += __shfl(v, c, 64) * k3b[c * 64 + lane];
  mb[n * 64 + lane] = mbv;
}

// ---------------- fallback-path kernels (round-2 Plan C, proven) ----------------
__global__ void h0_kernel(const float* __restrict__ x, const float* __restrict__ fc1w,
                          const float* __restrict__ fc1b, float* __restrict__ h) {
  int idx = blockIdx.x * blockDim.x + threadIdx.x;
  if (idx >= NN * WIDTH) return;
  int n = idx >> 6, w = idx & 63;
  h[idx] = x[n] * fc1w[w] + fc1b[w];
}

__global__ void msg_kernel(const float* __restrict__ h, const unsigned short* __restrict__ Wc,
                           const int* __restrict__ src, const int* __restrict__ dst,
                           float* __restrict__ agg, int e0, int e_end) {
  int wave = threadIdx.x >> 6;
  int lane = threadIdx.x & 63;
  int e = e0 + blockIdx.x * 4 + wave;
  if (e >= e_end) return;
  int s = src[e], d = dst[e];
  float hv = h[s * WIDTH + lane];
  const unsigned short* We = Wc + (long long)(e - e0) * 4096;
  float acc = 0.f;
#pragma unroll
  for (int c = 0; c < 64; c++) {
    float hs = __shfl(hv, c, 64);
    acc += hs * bf2f(We[c * 64 + lane]);
  }
  atomicAdd(&agg[d * WIDTH + lane], acc);
}

__global__ void update_kernel(const float* __restrict__ h, const float* __restrict__ agg,
                              const float* __restrict__ deg, const float* __restrict__ root,
                              const float* __restrict__ convb, float* __restrict__ hout,
                              int do_relu) {
  int wave = threadIdx.x >> 6, lane = threadIdx.x & 63;
  int n = blockIdx.x * 4 + wave;
  if (n >= NN) return;
  float hv = h[n * WIDTH + lane];
  float acc = 0.f;
#pragma unroll
  for (int c = 0; c < 64; c++)
    acc += __shfl(hv, c, 64) * root[c * WIDTH + lane];
  float dg = deg[n];
  float inv = dg > 0.f ? 1.0f / dg : 0.f;
  float v = agg[n * WIDTH + lane] * inv + acc + convb[lane];
  if (do_relu) v = fmaxf(v, 0.f);
  hout[n * WIDTH + lane] = v;
}

__global__ void fc2_kernel(const float* __restrict__ h, const float* __restrict__ fc2w,
                           const float* __restrict__ fc2b, float* __restrict__ out) {
  int wave = threadIdx.x >> 6, lane = threadIdx.x & 63;
  int n = blockIdx.x * 4 + wave;
  if (n >= NN) return;
  float v = h[n * WIDTH + lane] * fc2w[lane];
#pragma unroll
  for (int off = 32; off > 0; off >>= 1) v += __shfl_down(v, off, 64);
  if (lane == 0) out[n] = v + fc2b[0];
}

extern "C" void kernel_launch(void* const* d_in, const int* in_sizes, int n_in,
                              void* d_out, int out_size, void* d_ws, size_t ws_size,
                              hipStream_t stream) {
  const float* x     = (const float*)d_in[0];
  const int*   ei    = (const int*)d_in[1];
  const float* ea    = (const float*)d_in[2];
  const float* fc1w  = (const float*)d_in[3];
  const float* fc1b  = (const float*)d_in[4];
  const float* k1w   = (const float*)d_in[5];
  const float* k1b   = (const float*)d_in[6];
  const float* k2w   = (const float*)d_in[7];
  const float* k2b   = (const float*)d_in[8];
  const float* k3w   = (const float*)d_in[9];
  const float* k3b   = (const float*)d_in[10];
  const float* root  = (const float*)d_in[11];
  const float* convb = (const float*)d_in[12];
  const float* fc2w  = (const float*)d_in[13];
  const float* fc2b  = (const float*)d_in[14];
  float* out = (float*)d_out;
  const int* src = ei;
  const int* dst = ei + NE;

  char* ws = (char*)d_ws;
  size_t off = 0;
  auto alloc = [&](size_t bytes) -> char* {
    char* p = ws + off; off = (off + bytes + 255) & ~(size_t)255; return p;
  };
  auto al = [](size_t x) { return (x + 255) & ~(size_t)255; };

  // ---- common ----
  unsigned short* k2wT = (unsigned short*)alloc((size_t)KW * KW * 2);
  float* ha  = (float*)alloc((size_t)NN * WIDTH * 4);
  float* hb  = (float*)alloc((size_t)NN * WIDTH * 4);
  float* agg = (float*)alloc((size_t)NN * WIDTH * 4);
  float* deg = (float*)alloc((size_t)NN * 4);
  if (ws_size < off + 4096) return;

  const size_t PT_CH = 128 * KW * 2;  // 262144

  size_t sz_kpt  = (size_t)(64 << 16) * 2;     // kp3: 8.39 MB
  size_t sz_mb   = (size_t)NN * 64 * 4;
  size_t sz_hbf  = (size_t)NN_PAD * 64 * 2;
  size_t sz_cnt  = (size_t)NN * 4;
  size_t sz_st   = (size_t)(NN + 1) * 4;
  size_t sz_sid  = (size_t)NE * 4;
  size_t sz_e2   = (size_t)E_PAD * KW * 2;     // e2p
  size_t sz_tiles = (size_t)NGRP2 * 4 * MAXSETS * 8;

  size_t core = al(sz_kpt) + al(sz_mb) + al(sz_hbf) + al(sz_cnt) + al(sz_st) + al(sz_cnt)
              + al(sz_sid) + al(sz_e2) + al(sz_tiles) + al(sz_sid) /*pose*/;
  size_t msg_csr = al(sz_cnt) + al(sz_st) + al(sz_cnt) + al(sz_sid);
  size_t e1c_min = al((size_t)8 * PT_CH);

  int msg_mode;  // 2 = fp32 msg buffer, 1 = bf16 msg buffer, 0 = atomic agg, -1 = Plan C
  if (ws_size >= off + core + msg_csr + al((size_t)NE * 64 * 4) + e1c_min)       msg_mode = 2;
  else if (ws_size >= off + core + msg_csr + al((size_t)NE * 64 * 2) + e1c_min)  msg_mode = 1;
  else if (ws_size >= off + core + e1c_min + 8192)                               msg_mode = 0;
  else                                                                           msg_mode = -1;

  if (msg_mode >= 0) {
    // ================= FUSED d-TRICK PATH (v12 = v9 fused + sorted prologue) =========
    unsigned short* kp3 = (unsigned short*)alloc(sz_kpt);
    float* mb   = (float*)alloc(sz_mb);
    unsigned short* hbf = (unsigned short*)alloc(sz_hbf);
    int* cnt    = (int*)alloc(sz_cnt);
    int* starta = (int*)alloc(sz_st);
    int* cursor = (int*)alloc(sz_cnt);
    int* sid    = (int*)alloc(sz_sid);
    unsigned short* e2p = (unsigned short*)alloc(sz_e2);
    int2* tiles = (int2*)alloc(sz_tiles);
    int* pose   = (int*)alloc(sz_sid);
    int* cnt2 = nullptr; int* startd = nullptr;
    int* cursor2 = nullptr; int* sid2 = nullptr;
    unsigned short* msgh = nullptr; float* msgf = nullptr;
    if (msg_mode >= 1) {
      cnt2    = (int*)alloc(sz_cnt);
      startd  = (int*)alloc(sz_st);
      cursor2 = (int*)alloc(sz_cnt);
      sid2    = (int*)alloc(sz_sid);
      if (msg_mode == 2) msgf = (float*)alloc((size_t)NE * 64 * 4);
      else               msgh = (unsigned short*)alloc((size_t)NE * 64 * 2);
    }
    size_t left = ws_size - off;
    int TC = (int)(left / PT_CH); if (TC > 98) TC = 98;
    unsigned short* e1c = (unsigned short*)alloc((size_t)TC * PT_CH);

    convert_transpose_kernel<<<(KW * KW) / 256, 256, 0, stream>>>(k2w, k2wT, KW, KW);
    build_kpt3_kernel<<<(64 << 16) / 256, 256, 0, stream>>>(k3w, kp3);
    hipMemsetAsync(cnt, 0, sz_cnt, stream);
    count_kernel<<<(NE + 255) / 256, 256, 0, stream>>>(src, cnt, NE);
    scan_kernel<<<1, 1024, 0, stream>>>(cnt, starta, cursor);
    scatter_kernel<<<(NE + 255) / 256, 256, 0, stream>>>(src, cursor, sid, pose, NE);
    build_tiles_kernel<<<(NGRP2 + 255) / 256, 256, 0, stream>>>(starta, tiles);
    if (msg_mode >= 1) {
      hipMemsetAsync(cnt2, 0, sz_cnt, stream);
      count_kernel<<<(NE + 255) / 256, 256, 0, stream>>>(dst, cnt2, NE);
      scan_kernel<<<1, 1024, 0, stream>>>(cnt2, startd, cursor2);
      scatter2_kernel<<<(NE + 255) / 256, 256, 0, stream>>>(dst, cursor2, pose, sid2, NE);
    } else {
      hipMemsetAsync(deg, 0, (size_t)NN * 4, stream);
      deg_kernel<<<(NE + 255) / 256, 256, 0, stream>>>(dst, deg, NE);
    }
    h0_mb_kernel<<<(NN + 3) / 4, 256, 0, stream>>>(x, fc1w, fc1b, k3b, ha, hbf, mb);
    // e1 gathered via sid (sorted order) -> gemm2 writes e2p contiguously
    for (int t0 = 0; t0 < MT_ALL; t0 += TC) {
      int tc = (MT_ALL - t0 < TC) ? (MT_ALL - t0) : TC;
      gemm1_kernel<<<tc * 128, 256, 0, stream>>>(ea, k1w, k1b, sid, e1c, t0 * 128, NE);
      gemm_bt_kernel<<<tc * (KW / 128), 256, 0, stream>>>(
          e1c, k2wT, k2b, e2p, t0 * 128, KW, KW, tc, 1, 1);
    }
    float* hc = ha; float* hn = hb;
    for (int k = 0; k < DEPTH; k++) {
      if (msg_mode == 0) hipMemsetAsync(agg, 0, (size_t)NN * WIDTH * 4, stream);
      fused_msg_kernel<<<4 * NGRP2, 256, 0, stream>>>(
          hbf, e2p, kp3, tiles, sid, dst, mb, agg, msgh, msgf, msg_mode);
      if (msg_mode >= 1)
        scatter_update_mb_kernel<<<(NN + 3) / 4, 256, 0, stream>>>(
            msgh, msgf, startd, sid2, hc, root, convb, k3b, hn, hbf, mb,
            (k != DEPTH - 1) ? 1 : 0, msg_mode);
      else
        update_mb_kernel<<<(NN + 3) / 4, 256, 0, stream>>>(
            hc, agg, deg, root, convb, k3b, hn, hbf, mb, (k != DEPTH - 1) ? 1 : 0);
      float* t = hc; hc = hn; hn = t;
    }
    fc2_kernel<<<(NN + 3) / 4, 256, 0, stream>>>(hc, fc2w, fc2b, out);
  } else {
    // ================= FALLBACK: round-2 Plan C (proven) =================
    unsigned short* k3wT = (unsigned short*)alloc((size_t)4096 * KW * 2);
    size_t rem = (ws_size > off) ? ws_size - off : 0;
    const size_t PT_W = 128 * 4096 * 2;
    size_t per_tile = 2 * PT_CH + PT_W;
    long long tcl = (long long)(rem / per_tile);
    int TC = (tcl > 98) ? 98 : (int)tcl;
    if (TC < 1) return;
    unsigned short* e1c = (unsigned short*)alloc((size_t)TC * PT_CH);
    unsigned short* e2c = (unsigned short*)alloc((size_t)TC * PT_CH);
    unsigned short* Wc  = (unsigned short*)alloc((size_t)TC * PT_W);

    convert_transpose_kernel<<<(KW * KW) / 256, 256, 0, stream>>>(k2w, k2wT, KW, KW);
    convert_transpose_kernel<<<(KW * 4096) / 256, 256, 0, stream>>>(k3w, k3wT, KW, 4096);
    hipMemsetAsync(deg, 0, (size_t)NN * 4, stream);
    deg_kernel<<<(NE + 255) / 256, 256, 0, stream>>>(dst, deg, NE);
    h0_kernel<<<(NN * WIDTH) / 256, 256, 0, stream>>>(x, fc1w, fc1b, ha);

    float* hc = ha; float* hn = hb;
    for (int k = 0; k < DEPTH; k++) {
      hipMemsetAsync(agg, 0, (size_t)NN * WIDTH * 4, stream);
      for (int t0 = 0; t0 < MT_ALL; t0 += TC) {
        int tc = (MT_ALL - t0 < TC) ? (MT_ALL - t0) : TC;
        gemm1_kernel<<<tc * 128, 256, 0, stream>>>(ea, k1w, k1b, nullptr, e1c, t0 * 128, NE);
        gemm_bt_kernel<<<tc * (KW / 128), 256, 0, stream>>>(e1c, k2wT, k2b, e2c,
                                                            0, KW, KW, tc, 1, 0);
        gemm_bt_kernel<<<tc * (4096 / 128), 256, 0, stream>>>(e2c, k3wT, k3b, Wc,
                                                              0, 4096, KW, tc, 0, 0);
        int e0 = t0 * 128;
        int e_end = (t0 + tc) * 128; if (e_end > NE) e_end = NE;
        if (e_end > e0)
          msg_kernel<<<(e_end - e0 + 3) / 4, 256, 0, stream>>>(hc, Wc, src, dst, agg, e0, e_end);
      }
      update_kernel<<<(NN + 3) / 4, 256, 0, stream>>>(hc, agg, deg, root, convb, hn,
                                                      (k != DEPTH - 1) ? 1 : 0);
      float* t = hc; hc = hn; hn = t;
    }
    fc2_kernel<<<(NN + 3) / 4, 256, 0, stream>>>(hc, fc2w, fc2b, out);
  }
}

// Round 15
// 4037.250 us; speedup vs baseline: 1.5179x; 1.0113x over previous
//
#include <hip/hip_runtime.h>
#include <hip/hip_bf16.h>

#define WIDTH 64
#define KW 1024
#define DEPTH 6
#define NN 10000
#define NE 100000
#define E_PAD 100096          // 782 * 128
#define MT_ALL (E_PAD / 128)  // 782 M-tiles
#define GNODES 32
#define MAXSETS 12
#define NGRP2 313             // ceil(NN / GNODES)
#define NN_PAD (NGRP2 * GNODES)  // 10016
#define G1E 16                // edges per gemm1 block

typedef __attribute__((ext_vector_type(8))) short bf16x8;
typedef __attribute__((ext_vector_type(4))) float f32x4;

#define AS1 __attribute__((address_space(1)))
#define AS3 __attribute__((address_space(3)))

__device__ __forceinline__ float bf2f(unsigned short u) {
  union { unsigned int i; float f; } v; v.i = ((unsigned int)u) << 16; return v.f;
}
__device__ __forceinline__ unsigned short f2bf(float f) {
  union { float f; unsigned int i; } v; v.f = f;
  return (unsigned short)((v.i + 0x7FFFu + ((v.i >> 16) & 1u)) >> 16);  // RNE
}

__device__ __forceinline__ void gl_lds16(const void* g, void* lds_base) {
#if __has_builtin(__builtin_amdgcn_global_load_lds)
  __builtin_amdgcn_global_load_lds((const AS1 unsigned int*)g,
                                   (AS3 unsigned int*)lds_base, 16, 0, 0);
#else
  *(uint4*)((char*)lds_base + (threadIdx.x & 63) * 16) = *(const uint4*)g;
#endif
}

// ---------------- weight fp32 -> bf16 transpose: out[n][k] = in[k][n] ----------------
__global__ void convert_transpose_kernel(const float* __restrict__ in,
                                         unsigned short* __restrict__ out,
                                         int K, int N) {
  long long idx = (long long)blockIdx.x * blockDim.x + threadIdx.x;
  if (idx >= (long long)K * N) return;
  int k = (int)(idx % K);
  int n = (int)(idx / K);
  out[idx] = f2bf(in[(long long)k * N + n]);
}

// -------- kp3: k3w repacked into producer MFMA-fragment order ---------------------
// kp3[(((o*32 + rt)*2 + hh)*2 + chalf)*512 + lane*8 + j] =
//   bf16(k3w[r*4096 + c*64 + o]),  r = rt*32 + hh*16 + (lane&15),
//                                  c = chalf*32 + (lane>>4)*8 + j.
__global__ void build_kpt3_kernel(const float* __restrict__ k3w,
                                  unsigned short* __restrict__ kp3) {
  int idx = blockIdx.x * blockDim.x + threadIdx.x;  // 64<<16 = 4,194,304
  if (idx >= (64 << 16)) return;
  int j     = idx & 7;
  int lane  = (idx >> 3) & 63;
  int chalf = (idx >> 9) & 1;
  int hh    = (idx >> 10) & 1;
  int rt    = (idx >> 11) & 31;
  int o     = idx >> 16;
  int r = rt * 32 + hh * 16 + (lane & 15);
  int c = chalf * 32 + (lane >> 4) * 8 + j;
  kp3[idx] = f2bf(k3w[(long long)r * 4096 + c * 64 + o]);
}

// --------- gemm1 v2: 16 edges per block; k1w tile in registers reused 16x ----------
// e1 row p (src-sorted order) = relu(ea[sid[p]] @ k1_w + k1_b), bf16 out.
__global__ void gemm1_kernel(const float* __restrict__ ea, const float* __restrict__ k1w,
                             const float* __restrict__ k1b, const int* __restrict__ sid,
                             unsigned short* __restrict__ e1c, int e0, int E) {
  __shared__ float af[G1E][6];
  int t = threadIdx.x;
  int p0 = e0 + blockIdx.x * G1E;
  if (t < G1E * 6) {
    int le = t / 6, j = t - le * 6;
    int p = p0 + le;
    int e = (p < E) ? (sid ? sid[p] : p) : -1;
    af[le][j] = (e >= 0) ? ea[(long long)e * 6 + j] : 0.0f;
  }
  __syncthreads();
  int c4 = t * 4;
  float4 b4 = *(const float4*)&k1b[c4];
  float4 w[6];
#pragma unroll
  for (int j = 0; j < 6; j++) w[j] = *(const float4*)&k1w[j * KW + c4];
#pragma unroll 4
  for (int le = 0; le < G1E; le++) {
    float a0 = b4.x, a1 = b4.y, a2 = b4.z, a3 = b4.w;
#pragma unroll
    for (int j = 0; j < 6; j++) {
      float av = af[le][j];  // LDS broadcast (same addr all lanes)
      a0 += av * w[j].x; a1 += av * w[j].y; a2 += av * w[j].z; a3 += av * w[j].w;
    }
    ushort4 o;
    o.x = f2bf(fmaxf(a0, 0.f)); o.y = f2bf(fmaxf(a1, 0.f));
    o.z = f2bf(fmaxf(a2, 0.f)); o.w = f2bf(fmaxf(a3, 0.f));
    *(ushort4*)&e1c[(long long)(blockIdx.x * G1E + le) * KW + c4] = o;
  }
}

// ------- bf16 GEMM: C = A @ BT^T + bias, opt relu ---------------------------------
// kblocked: write C in K-blocked layout C[(n>>5)*E_PAD + (row0+m)][n&31], rows
// contiguous (input already src-sorted).
__global__ __launch_bounds__(256, 2)
void gemm_bt_kernel(const unsigned short* __restrict__ A,
                    const unsigned short* __restrict__ BT,
                    const float* __restrict__ bias,
                    unsigned short* __restrict__ C,
                    int row0, int N, int K, int mtiles, int do_relu, int kblocked) {
  __shared__ unsigned short sA[128 * 64];
  __shared__ unsigned short sB[128 * 64];
  const int tid  = threadIdx.x;
  const int wave = tid >> 6;
  const int lane = tid & 63;
  const int mt = blockIdx.x % mtiles;
  const int nt = blockIdx.x / mtiles;
  const long long m0 = (long long)mt * 128;
  const int n0 = nt * 128;
  const int wm = wave >> 1, wn = wave & 1;
  const int l15 = lane & 15, quad = lane >> 4;

  f32x4 acc[4][4];
#pragma unroll
  for (int i = 0; i < 4; i++)
#pragma unroll
    for (int j = 0; j < 4; j++) { f32x4 z = {0.f, 0.f, 0.f, 0.f}; acc[i][j] = z; }

  int a_off[4][2], b_off[4][2];
#pragma unroll
  for (int i = 0; i < 4; i++) {
    int ra = wm * 64 + i * 16 + l15;
    int rb = wn * 64 + i * 16 + l15;
#pragma unroll
    for (int kk = 0; kk < 2; kk++) {
      int q = kk * 4 + quad;
      a_off[i][kk] = (ra * 8 + (q ^ (ra & 7))) * 16;
      b_off[i][kk] = (rb * 8 + (q ^ (rb & 7))) * 16;
    }
  }

  int st_row[4], st_q[4];
#pragma unroll
  for (int t = 0; t < 4; t++) {
    int p = (wave * 4 + t) * 64 + lane;
    st_row[t] = p >> 3;
    st_q[t] = (p & 7) ^ ((p >> 3) & 7);
  }

  for (int k0 = 0; k0 < K; k0 += 64) {
    __syncthreads();
#pragma unroll
    for (int t = 0; t < 4; t++) {
      const unsigned short* ga = A + (m0 + st_row[t]) * K + (k0 + st_q[t] * 8);
      const unsigned short* gb = BT + ((long long)(n0 + st_row[t])) * K + (k0 + st_q[t] * 8);
      gl_lds16(ga, (void*)&sA[(wave * 4 + t) * 64 * 8]);
      gl_lds16(gb, (void*)&sB[(wave * 4 + t) * 64 * 8]);
    }
    __syncthreads();

#pragma unroll
    for (int kk = 0; kk < 2; kk++) {
      bf16x8 af[4], bfr[4];
#pragma unroll
      for (int i = 0; i < 4; i++) af[i]  = *(const bf16x8*)((const char*)sA + a_off[i][kk]);
#pragma unroll
      for (int i = 0; i < 4; i++) bfr[i] = *(const bf16x8*)((const char*)sB + b_off[i][kk]);
#pragma unroll
      for (int mi = 0; mi < 4; mi++)
#pragma unroll
        for (int ni = 0; ni < 4; ni++)
          acc[mi][ni] = __builtin_amdgcn_mfma_f32_16x16x32_bf16(af[mi], bfr[ni], acc[mi][ni], 0, 0, 0);
    }
  }

  float bias_v[4];
#pragma unroll
  for (int ni = 0; ni < 4; ni++) bias_v[ni] = bias[n0 + wn * 64 + ni * 16 + l15];
#pragma unroll
  for (int mi = 0; mi < 4; mi++) {
#pragma unroll
    for (int ni = 0; ni < 4; ni++) {
#pragma unroll
      for (int r = 0; r < 4; r++) {
        long long m = m0 + wm * 64 + mi * 16 + quad * 4 + r;
        int n = n0 + wn * 64 + ni * 16 + l15;
        float v = acc[mi][ni][r] + bias_v[ni];
        if (do_relu) v = fmaxf(v, 0.f);
        if (kblocked)
          C[((long long)(n >> 5) * E_PAD + (row0 + m)) * 32 + (n & 31)] = f2bf(v);
        else
          C[m * N + n] = f2bf(v);
      }
    }
  }
}

// ---------------- degree (by dst, fp32) ----------------
__global__ void deg_kernel(const int* __restrict__ dst, float* __restrict__ deg, int E) {
  int e = blockIdx.x * blockDim.x + threadIdx.x;
  if (e < E) atomicAdd(&deg[dst[e]], 1.0f);
}

// ---------------- counting sort (generic by key array) ----------------
__global__ void count_kernel(const int* __restrict__ key, int* __restrict__ cnt, int E) {
  int e = blockIdx.x * blockDim.x + threadIdx.x;
  if (e < E) atomicAdd(&cnt[key[e]], 1);
}

__global__ void scan_kernel(const int* __restrict__ cnt, int* __restrict__ start,
                            int* __restrict__ cursor) {
  __shared__ int psum[1024];
  int t = threadIdx.x;
  int s0 = t * 10;
  int vals[10];
  int local = 0;
#pragma unroll
  for (int i = 0; i < 10; i++) {
    int idx = s0 + i;
    vals[i] = (idx < NN) ? cnt[idx] : 0;
    local += vals[i];
  }
  psum[t] = local;
  __syncthreads();
  for (int off = 1; off < 1024; off <<= 1) {
    int v = (t >= off) ? psum[t - off] : 0;
    __syncthreads();
    psum[t] += v;
    __syncthreads();
  }
  int excl = psum[t] - local;
#pragma unroll
  for (int i = 0; i < 10; i++) {
    int idx = s0 + i;
    if (idx < NN) { start[idx] = excl; cursor[idx] = excl; excl += vals[i]; }
  }
  if (t == 0) start[NN] = NE;
}

// scatter by src; also records pose[e] = src-sorted position of edge e
__global__ void scatter_kernel(const int* __restrict__ src, int* __restrict__ cursor,
                               int* __restrict__ sorted_eid, int* __restrict__ pose, int E) {
  int e = blockIdx.x * blockDim.x + threadIdx.x;
  if (e < E) {
    int pos = atomicAdd(&cursor[src[e]], 1);
    sorted_eid[pos] = e;
    pose[e] = pos;
  }
}

// scatter by dst storing src-sorted positions: dst-CSR of msg rows
__global__ void scatter2_kernel(const int* __restrict__ dst, int* __restrict__ cursor2,
                                const int* __restrict__ pose, int* __restrict__ sid2, int E) {
  int e = blockIdx.x * blockDim.x + threadIdx.x;
  if (e < E) {
    int pos = atomicAdd(&cursor2[dst[e]], 1);
    sid2[pos] = pose[e];
  }
}

// ---------------- per-(group,wave) static tile lists: topology-only, built once -------
__global__ void build_tiles_kernel(const int* __restrict__ start, int2* __restrict__ tiles) {
  int g = blockIdx.x * blockDim.x + threadIdx.x;
  if (g >= NGRP2) return;
  int nt[4] = {0, 0, 0, 0};
  for (int w = 0; w < 4; w++)
    for (int s = 0; s < MAXSETS; s++)
      tiles[(g * 4 + w) * MAXSETS + s] = make_int2(0, 0);
  int t = 0;
  for (int i = 0; i < GNODES; i++) {
    int na = g * GNODES + i;
    int nb = na + 1;
    if (na > NN) na = NN;
    if (nb > NN) nb = NN;
    int s = start[na], e = start[nb];
    for (int m0 = s; m0 < e; m0 += 16) {
      int w = t & 3;
      if (nt[w] < MAXSETS) {
        int c = e - m0; if (c > 16) c = 16;
        tiles[(g * 4 + w) * MAXSETS + nt[w]] = make_int2(i | (c << 16), m0);
        nt[w]++;
      }
      t++;
    }
  }
}

// ---------------- h0 (+ bf16 copy + msg-bias) ----------------
__global__ void h0_mb_kernel(const float* __restrict__ x, const float* __restrict__ fc1w,
                             const float* __restrict__ fc1b, const float* __restrict__ k3b,
                             float* __restrict__ h, unsigned short* __restrict__ hbf,
                             float* __restrict__ mb) {
  int wave = threadIdx.x >> 6, lane = threadIdx.x & 63;
  int n = blockIdx.x * 4 + wave;
  if (n >= NN) return;
  float v = x[n] * fc1w[lane] + fc1b[lane];
  h[n * 64 + lane] = v;
  hbf[n * 64 + lane] = f2bf(v);
  float mbv = 0.f;
#pragma unroll
  for (int c = 0; c < 64; c++)
    mbv += __shfl(v, c, 64) * k3b[c * 64 + lane];
  mb[n * 64 + lane] = mbv;
}

// ---------------- fused per-depth message kernel (d-trick, v12 structure) ----------
// Best measured: ~380 us. Single 32 KB slab, 2 barriers/rt, e2p prefetch after
// barrier-1 overlapping produce; coalesced kp3 + e2p 1 KB wave-loads.
// launch_bounds(256,3): 84 VGPR, NO SPILLS. (256,4) -> 64-VGPR step + scratch
// spills (+500 MB WRITE, 2x dur) — measured round 13. DO NOT CHANGE.
__global__ __launch_bounds__(256, 3)
void fused_msg_kernel(const unsigned short* __restrict__ hbf,
                      const unsigned short* __restrict__ e2p,
                      const unsigned short* __restrict__ kp3,
                      const int2* __restrict__ tiles,
                      const int* __restrict__ sorted_eid,
                      const int* __restrict__ dst,
                      const float* __restrict__ mb,
                      float* __restrict__ agg,
                      unsigned short* __restrict__ msgh,
                      float* __restrict__ msgf,
                      int msg_mode) {
  __shared__ unsigned short slab[GNODES * 512];  // 32 nodes x 16 o x 32 r = 32 KB
  const int tid = threadIdx.x, wave = tid >> 6, lane = tid & 63;
  const int l15 = lane & 15, quad = lane >> 4;
  const int oh = blockIdx.x & 3;           // XCD-pinned o-quarter
  const int ng = blockIdx.x >> 2;
  const int n0 = ng * GNODES;

  // ---- load static slots ----
  int s_node[MAXSETS], s_j[MAXSETS], s_cnt[MAXSETS], row_off[MAXSETS];
  const int2* tp = tiles + (ng * 4 + wave) * MAXSETS;
#pragma unroll
  for (int s2 = 0; s2 < MAXSETS; s2++) {
    int2 rec = tp[s2];
    s_node[s2] = rec.x & 0xffff;
    s_cnt[s2]  = rec.x >> 16;
    s_j[s2]    = rec.y;
    int c = s_cnt[s2];
    int sl = (l15 < c) ? l15 : (c > 0 ? c - 1 : 0);
    row_off[s2] = (s_j[s2] + sl) * 32 + quad * 8;  // within an rt-slice of e2p
  }

  f32x4 acc[MAXSETS];
#pragma unroll
  for (int s2 = 0; s2 < MAXSETS; s2++) { f32x4 z = {0.f, 0.f, 0.f, 0.f}; acc[s2] = z; }

  // producer B-frags (n = node), two 16-node halves, loop-invariant
  bf16x8 pb0[2], pb1[2];
#pragma unroll
  for (int g2 = 0; g2 < 2; g2++) {
    pb0[g2] = *(const bf16x8*)(hbf + (n0 + g2 * 16 + l15) * 64 + quad * 8);
    pb1[g2] = *(const bf16x8*)(hbf + (n0 + g2 * 16 + l15) * 64 + 32 + quad * 8);
  }

  for (int rt = 0; rt < 32; rt++) {
    __syncthreads();  // WAR: prev consume done before overwrite
    // prefetch consumer e2p frags (coalesced 1 KB wave-loads; overlap produce)
    const unsigned short* e2s = e2p + (size_t)rt * (E_PAD * 32);
    bf16x8 apre[MAXSETS];
#pragma unroll
    for (int s2 = 0; s2 < MAXSETS; s2++) {
      if (s_cnt[s2])  // wave-uniform
        apre[s2] = *(const bf16x8*)(e2s + row_off[s2]);
    }
    // ---- produce: 32 m-tiles (o_loc 16 x hh 2), wave covers 8, coalesced kp3 ----
#pragma unroll 4
    for (int u = 0; u < 8; u++) {
      int id = wave * 8 + u;
      int o_loc = id >> 1, hh = id & 1;
      int o = oh * 16 + o_loc;
      const unsigned short* blk = kp3 + (size_t)(((o * 32 + rt) * 2 + hh) * 2) * 512;
      bf16x8 a0 = *(const bf16x8*)(blk + lane * 8);          // chalf 0
      bf16x8 a1 = *(const bf16x8*)(blk + 512 + lane * 8);    // chalf 1
      int chunk_log = o_loc * 4 + hh * 2 + (quad >> 1);
      int phys = chunk_log ^ (l15 & 7);
#pragma unroll
      for (int g2 = 0; g2 < 2; g2++) {
        f32x4 c = {0.f, 0.f, 0.f, 0.f};
        c = __builtin_amdgcn_mfma_f32_16x16x32_bf16(a0, pb0[g2], c, 0, 0, 0);
        c = __builtin_amdgcn_mfma_f32_16x16x32_bf16(a1, pb1[g2], c, 0, 0, 0);
        // lane: node = g2*16 + l15, r_loc = hh*16 + quad*4 + reg -> one b64
        unsigned int w0 = (unsigned int)f2bf(c[0]) | ((unsigned int)f2bf(c[1]) << 16);
        unsigned int w1 = (unsigned int)f2bf(c[2]) | ((unsigned int)f2bf(c[3]) << 16);
        uint2* p = (uint2*)((char*)slab + (g2 * 16 + l15) * 1024 + phys * 16 + (quad & 1) * 8);
        uint2 w; w.x = w0; w.y = w1;
        *p = w;
      }
    }
    __syncthreads();  // RAW: slab ready
    // ---- consume: static slots, one k=32 MFMA each ----
#pragma unroll
    for (int s2 = 0; s2 < MAXSETS; s2++) {
      if (s_cnt[s2] == 0) continue;  // wave-uniform
      int node = s_node[s2];
      const char* nb = (const char*)slab + node * 1024;
      bf16x8 b = *(const bf16x8*)(nb + (((l15 * 4 + quad) ^ (node & 7)) * 16));
      acc[s2] = __builtin_amdgcn_mfma_f32_16x16x32_bf16(apre[s2], b, acc[s2], 0, 0, 0);
    }
  }

  // ---- epilogue (static slots), o-quarter slice ----
#pragma unroll
  for (int s2 = 0; s2 < MAXSETS; s2++) {
    if (s_cnt[s2] == 0) continue;  // wave-uniform
    float mbv = mb[(n0 + s_node[s2]) * 64 + oh * 16 + l15];
#pragma unroll
    for (int reg = 0; reg < 4; reg++) {
      int mloc = quad * 4 + reg;
      if (mloc < s_cnt[s2]) {
        int p = s_j[s2] + mloc;  // src-sorted position
        float v = acc[s2][reg] + mbv;
        if (msg_mode == 2) {
          __builtin_nontemporal_store(v, &msgf[p * 64 + oh * 16 + l15]);
        } else if (msg_mode == 1) {
          __builtin_nontemporal_store(f2bf(v), &msgh[p * 64 + oh * 16 + l15]);
        } else {
          int d = dst[sorted_eid[p]];
          atomicAdd(&agg[d * 64 + oh * 16 + l15], v);
        }
      }
    }
  }
}

// -------- gather msg rows by dst-CSR + full node update (+hbf/mb for next depth) --------
__global__ void scatter_update_mb_kernel(const unsigned short* __restrict__ msgh,
                                         const float* __restrict__ msgf,
                                         const int* __restrict__ startd,
                                         const int* __restrict__ sid2,
                                         const float* __restrict__ h,
                                         const float* __restrict__ root,
                                         const float* __restrict__ convb,
                                         const float* __restrict__ k3b,
                                         float* __restrict__ hout,
                                         unsigned short* __restrict__ hbf,
                                         float* __restrict__ mb,
                                         int do_relu, int msg_mode) {
  int wave = threadIdx.x >> 6, lane = threadIdx.x & 63;
  int n = blockIdx.x * 4 + wave;
  if (n >= NN) return;
  float hv = h[n * 64 + lane];
  float racc = 0.f;
#pragma unroll
  for (int c = 0; c < 64; c++)
    racc += __shfl(hv, c, 64) * root[c * 64 + lane];
  int js = startd[n], je = startd[n + 1];
  float sum = 0.f;
  if (msg_mode == 2) {
    for (int j = js; j < je; j++) { int p = sid2[j]; sum += msgf[p * 64 + lane]; }
  } else {
    for (int j = js; j < je; j++) { int p = sid2[j]; sum += bf2f(msgh[p * 64 + lane]); }
  }
  float inv = (je > js) ? 1.0f / (float)(je - js) : 0.f;
  float v = sum * inv + racc + convb[lane];
  if (do_relu) v = fmaxf(v, 0.f);
  hout[n * 64 + lane] = v;
  hbf[n * 64 + lane] = f2bf(v);
  float mbv = 0.f;
#pragma unroll
  for (int c = 0; c < 64; c++)
    mbv += __shfl(v, c, 64) * k3b[c * 64 + lane];
  mb[n * 64 + lane] = mbv;
}

// -------- update (+ bf16 copy + msg-bias), atomic-agg variant --------
__global__ void update_mb_kernel(const float* __restrict__ h, const float* __restrict__ agg,
                                 const float* __restrict__ deg, const float* __restrict__ root,
                                 const float* __restrict__ convb, const float* __restrict__ k3b,
                                 float* __restrict__ hout, unsigned short* __restrict__ hbf,
                                 float* __restrict__ mb, int do_relu) {
  int wave = threadIdx.x >> 6, lane = threadIdx.x & 63;
  int n = blockIdx.x * 4 + wave;
  if (n >= NN) return;
  float hv = h[n * 64 + lane];
  float acc = 0.f;
#pragma unroll
  for (int c = 0; c < 64; c++)
    acc += __shfl(hv, c, 64) * root[c * 64 + lane];
  float dg = deg[n];
  float inv = dg > 0.f ? 1.0f / dg : 0.f;
  float v = agg[n * 64 + lane] * inv + acc + convb[lane];
  if (do_relu) v = fmaxf(v, 0.f);
  hout[n * 64 + lane] = v;
  hbf[n * 64 + lane] = f2bf(v);
  float mbv = 0.f;
#pragma unroll
  for (int c = 0; c < 64; c++)
    mbv += __shfl(v, c, 64) * k3b[c * 64 + lane];
  mb[n * 64 + lane] = mbv;
}

// ---------------- fallback-path kernels (round-2 Plan C, proven) ----------------
__global__ void h0_kernel(const float* __restrict__ x, const float* __restrict__ fc1w,
                          const float* __restrict__ fc1b, float* __restrict__ h) {
  int idx = blockIdx.x * blockDim.x + threadIdx.x;
  if (idx >= NN * WIDTH) return;
  int n = idx >> 6, w = idx & 63;
  h[idx] = x[n] * fc1w[w] + fc1b[w];
}

__global__ void msg_kernel(const float* __restrict__ h, const unsigned short* __restrict__ Wc,
                           const int* __restrict__ src, const int* __restrict__ dst,
                           float* __restrict__ agg, int e0, int e_end) {
  int wave = threadIdx.x >> 6;
  int lane = threadIdx.x & 63;
  int e = e0 + blockIdx.x * 4 + wave;
  if (e >= e_end) return;
  int s = src[e], d = dst[e];
  float hv = h[s * WIDTH + lane];
  const unsigned short* We = Wc + (long long)(e - e0) * 4096;
  float acc = 0.f;
#pragma unroll
  for (int c = 0; c < 64; c++) {
    float hs = __shfl(hv, c, 64);
    acc += hs * bf2f(We[c * 64 + lane]);
  }
  atomicAdd(&agg[d * WIDTH + lane], acc);
}

__global__ void update_kernel(const float* __restrict__ h, const float* __restrict__ agg,
                              const float* __restrict__ deg, const float* __restrict__ root,
                              const float* __restrict__ convb, float* __restrict__ hout,
                              int do_relu) {
  int wave = threadIdx.x >> 6, lane = threadIdx.x & 63;
  int n = blockIdx.x * 4 + wave;
  if (n >= NN) return;
  float hv = h[n * WIDTH + lane];
  float acc = 0.f;
#pragma unroll
  for (int c = 0; c < 64; c++)
    acc += __shfl(hv, c, 64) * root[c * WIDTH + lane];
  float dg = deg[n];
  float inv = dg > 0.f ? 1.0f / dg : 0.f;
  float v = agg[n * WIDTH + lane] * inv + acc + convb[lane];
  if (do_relu) v = fmaxf(v, 0.f);
  hout[n * WIDTH + lane] = v;
}

__global__ void fc2_kernel(const float* __restrict__ h, const float* __restrict__ fc2w,
                           const float* __restrict__ fc2b, float* __restrict__ out) {
  int wave = threadIdx.x >> 6, lane = threadIdx.x & 63;
  int n = blockIdx.x * 4 + wave;
  if (n >= NN) return;
  float v = h[n * WIDTH + lane] * fc2w[lane];
#pragma unroll
  for (int off = 32; off > 0; off >>= 1) v += __shfl_down(v, off, 64);
  if (lane == 0) out[n] = v + fc2b[0];
}

extern "C" void kernel_launch(void* const* d_in, const int* in_sizes, int n_in,
                              void* d_out, int out_size, void* d_ws, size_t ws_size,
                              hipStream_t stream) {
  const float* x     = (const float*)d_in[0];
  const int*   ei    = (const int*)d_in[1];
  const float* ea    = (const float*)d_in[2];
  const float* fc1w  = (const float*)d_in[3];
  const float* fc1b  = (const float*)d_in[4];
  const float* k1w   = (const float*)d_in[5];
  const float* k1b   = (const float*)d_in[6];
  const float* k2w   = (const float*)d_in[7];
  const float* k2b   = (const float*)d_in[8];
  const float* k3w   = (const float*)d_in[9];
  const float* k3b   = (const float*)d_in[10];
  const float* root  = (const float*)d_in[11];
  const float* convb = (const float*)d_in[12];
  const float* fc2w  = (const float*)d_in[13];
  const float* fc2b  = (const float*)d_in[14];
  float* out = (float*)d_out;
  const int* src = ei;
  const int* dst = ei + NE;

  char* ws = (char*)d_ws;
  size_t off = 0;
  auto alloc = [&](size_t bytes) -> char* {
    char* p = ws + off; off = (off + bytes + 255) & ~(size_t)255; return p;
  };
  auto al = [](size_t x) { return (x + 255) & ~(size_t)255; };

  // ---- common ----
  unsigned short* k2wT = (unsigned short*)alloc((size_t)KW * KW * 2);
  float* ha  = (float*)alloc((size_t)NN * WIDTH * 4);
  float* hb  = (float*)alloc((size_t)NN * WIDTH * 4);
  float* agg = (float*)alloc((size_t)NN * WIDTH * 4);
  float* deg = (float*)alloc((size_t)NN * 4);
  if (ws_size < off + 4096) return;

  const size_t PT_CH = 128 * KW * 2;  // 262144

  size_t sz_kpt  = (size_t)(64 << 16) * 2;     // kp3: 8.39 MB
  size_t sz_mb   = (size_t)NN * 64 * 4;
  size_t sz_hbf  = (size_t)NN_PAD * 64 * 2;
  size_t sz_cnt  = (size_t)NN * 4;
  size_t sz_st   = (size_t)(NN + 1) * 4;
  size_t sz_sid  = (size_t)NE * 4;
  size_t sz_e2   = (size_t)E_PAD * KW * 2;     // e2p
  size_t sz_tiles = (size_t)NGRP2 * 4 * MAXSETS * 8;

  size_t core = al(sz_kpt) + al(sz_mb) + al(sz_hbf) + al(sz_cnt) + al(sz_st) + al(sz_cnt)
              + al(sz_sid) + al(sz_e2) + al(sz_tiles) + al(sz_sid) /*pose*/;
  size_t msg_csr = al(sz_cnt) + al(sz_st) + al(sz_cnt) + al(sz_sid);
  size_t e1c_min = al((size_t)8 * PT_CH);

  int msg_mode;  // 2 = fp32 msg buffer, 1 = bf16 msg buffer, 0 = atomic agg, -1 = Plan C
  if (ws_size >= off + core + msg_csr + al((size_t)NE * 64 * 4) + e1c_min)       msg_mode = 2;
  else if (ws_size >= off + core + msg_csr + al((size_t)NE * 64 * 2) + e1c_min)  msg_mode = 1;
  else if (ws_size >= off + core + e1c_min + 8192)                               msg_mode = 0;
  else                                                                           msg_mode = -1;

  if (msg_mode >= 0) {
    // ================= FUSED d-TRICK PATH (v13 = v12 + gemm1v2 + big TC) ============
    unsigned short* kp3 = (unsigned short*)alloc(sz_kpt);
    float* mb   = (float*)alloc(sz_mb);
    unsigned short* hbf = (unsigned short*)alloc(sz_hbf);
    int* cnt    = (int*)alloc(sz_cnt);
    int* starta = (int*)alloc(sz_st);
    int* cursor = (int*)alloc(sz_cnt);
    int* sid    = (int*)alloc(sz_sid);
    unsigned short* e2p = (unsigned short*)alloc(sz_e2);
    int2* tiles = (int2*)alloc(sz_tiles);
    int* pose   = (int*)alloc(sz_sid);
    int* cnt2 = nullptr; int* startd = nullptr;
    int* cursor2 = nullptr; int* sid2 = nullptr;
    unsigned short* msgh = nullptr; float* msgf = nullptr;
    if (msg_mode >= 1) {
      cnt2    = (int*)alloc(sz_cnt);
      startd  = (int*)alloc(sz_st);
      cursor2 = (int*)alloc(sz_cnt);
      sid2    = (int*)alloc(sz_sid);
      if (msg_mode == 2) msgf = (float*)alloc((size_t)NE * 64 * 4);
      else               msgh = (unsigned short*)alloc((size_t)NE * 64 * 2);
    }
    size_t left = ws_size - off;
    int TC = (int)(left / PT_CH); if (TC > MT_ALL) TC = MT_ALL;
    unsigned short* e1c = (unsigned short*)alloc((size_t)TC * PT_CH);

    convert_transpose_kernel<<<(KW * KW) / 256, 256, 0, stream>>>(k2w, k2wT, KW, KW);
    build_kpt3_kernel<<<(64 << 16) / 256, 256, 0, stream>>>(k3w, kp3);
    hipMemsetAsync(cnt, 0, sz_cnt, stream);
    count_kernel<<<(NE + 255) / 256, 256, 0, stream>>>(src, cnt, NE);
    scan_kernel<<<1, 1024, 0, stream>>>(cnt, starta, cursor);
    scatter_kernel<<<(NE + 255) / 256, 256, 0, stream>>>(src, cursor, sid, pose, NE);
    build_tiles_kernel<<<(NGRP2 + 255) / 256, 256, 0, stream>>>(starta, tiles);
    if (msg_mode >= 1) {
      hipMemsetAsync(cnt2, 0, sz_cnt, stream);
      count_kernel<<<(NE + 255) / 256, 256, 0, stream>>>(dst, cnt2, NE);
      scan_kernel<<<1, 1024, 0, stream>>>(cnt2, startd, cursor2);
      scatter2_kernel<<<(NE + 255) / 256, 256, 0, stream>>>(dst, cursor2, pose, sid2, NE);
    } else {
      hipMemsetAsync(deg, 0, (size_t)NN * 4, stream);
      deg_kernel<<<(NE + 255) / 256, 256, 0, stream>>>(dst, deg, NE);
    }
    h0_mb_kernel<<<(NN + 3) / 4, 256, 0, stream>>>(x, fc1w, fc1b, k3b, ha, hbf, mb);
    // e1 gathered via sid (sorted order) -> gemm2 writes e2p contiguously
    for (int t0 = 0; t0 < MT_ALL; t0 += TC) {
      int tc = (MT_ALL - t0 < TC) ? (MT_ALL - t0) : TC;
      gemm1_kernel<<<tc * 128 / G1E, 256, 0, stream>>>(ea, k1w, k1b, sid, e1c, t0 * 128, NE);
      gemm_bt_kernel<<<tc * (KW / 128), 256, 0, stream>>>(
          e1c, k2wT, k2b, e2p, t0 * 128, KW, KW, tc, 1, 1);
    }
    float* hc = ha; float* hn = hb;
    for (int k = 0; k < DEPTH; k++) {
      if (msg_mode == 0) hipMemsetAsync(agg, 0, (size_t)NN * WIDTH * 4, stream);
      fused_msg_kernel<<<4 * NGRP2, 256, 0, stream>>>(
          hbf, e2p, kp3, tiles, sid, dst, mb, agg, msgh, msgf, msg_mode);
      if (msg_mode >= 1)
        scatter_update_mb_kernel<<<(NN + 3) / 4, 256, 0, stream>>>(
            msgh, msgf, startd, sid2, hc, root, convb, k3b, hn, hbf, mb,
            (k != DEPTH - 1) ? 1 : 0, msg_mode);
      else
        update_mb_kernel<<<(NN + 3) / 4, 256, 0, stream>>>(
            hc, agg, deg, root, convb, k3b, hn, hbf, mb, (k != DEPTH - 1) ? 1 : 0);
      float* t = hc; hc = hn; hn = t;
    }
    fc2_kernel<<<(NN + 3) / 4, 256, 0, stream>>>(hc, fc2w, fc2b, out);
  } else {
    // ================= FALLBACK: round-2 Plan C (proven) =================
    unsigned short* k3wT = (unsigned short*)alloc((size_t)4096 * KW * 2);
    size_t rem = (ws_size > off) ? ws_size - off : 0;
    const size_t PT_W = 128 * 4096 * 2;
    size_t per_tile = 2 * PT_CH + PT_W;
    long long tcl = (long long)(rem / per_tile);
    int TC = (tcl > 98) ? 98 : (int)tcl;
    if (TC < 1) return;
    unsigned short* e1c = (unsigned short*)alloc((size_t)TC * PT_CH);
    unsigned short* e2c = (unsigned short*)alloc((size_t)TC * PT_CH);
    unsigned short* Wc  = (unsigned short*)alloc((size_t)TC * PT_W);

    convert_transpose_kernel<<<(KW * KW) / 256, 256, 0, stream>>>(k2w, k2wT, KW, KW);
    convert_transpose_kernel<<<(KW * 4096) / 256, 256, 0, stream>>>(k3w, k3wT, KW, 4096);
    hipMemsetAsync(deg, 0, (size_t)NN * 4, stream);
    deg_kernel<<<(NE + 255) / 256, 256, 0, stream>>>(dst, deg, NE);
    h0_kernel<<<(NN * WIDTH) / 256, 256, 0, stream>>>(x, fc1w, fc1b, ha);

    float* hc = ha; float* hn = hb;
    for (int k = 0; k < DEPTH; k++) {
      hipMemsetAsync(agg, 0, (size_t)NN * WIDTH * 4, stream);
      for (int t0 = 0; t0 < MT_ALL; t0 += TC) {
        int tc = (MT_ALL - t0 < TC) ? (MT_ALL - t0) : TC;
        gemm1_kernel<<<tc * 128 / G1E, 256, 0, stream>>>(ea, k1w, k1b, nullptr, e1c,
                                                         t0 * 128, NE);
        gemm_bt_kernel<<<tc * (KW / 128), 256, 0, stream>>>(e1c, k2wT, k2b, e2c,
                                                            0, KW, KW, tc, 1, 0);
        gemm_bt_kernel<<<tc * (4096 / 128), 256, 0, stream>>>(e2c, k3wT, k3b, Wc,
                                                              0, 4096, KW, tc, 0, 0);
        int e0 = t0 * 128;
        int e_end = (t0 + tc) * 128; if (e_end > NE) e_end = NE;
        if (e_end > e0)
          msg_kernel<<<(e_end - e0 + 3) / 4, 256, 0, stream>>>(hc, Wc, src, dst, agg, e0, e_end);
      }
      update_kernel<<<(NN + 3) / 4, 256, 0, stream>>>(hc, agg, deg, root, convb, hn,
                                                      (k != DEPTH - 1) ? 1 : 0);
      float* t = hc; hc = hn; hn = t;
    }
    fc2_kernel<<<(NN + 3) / 4, 256, 0, stream>>>(hc, fc2w, fc2b, out);
  }
}

// Round 16
// 4020.795 us; speedup vs baseline: 1.5241x; 1.0041x over previous
//
#include <hip/hip_runtime.h>
#include <hip/hip_bf16.h>

#define WIDTH 64
#define KW 1024
#define DEPTH 6
#define NN 10000
#define NE 100000
#define E_PAD 100096          // 782 * 128
#define MT_ALL (E_PAD / 128)  // 782 M-tiles
#define GNODES 32
#define MAXSETS 12
#define NGRP2 313             // ceil(NN / GNODES)
#define NN_PAD (NGRP2 * GNODES)  // 10016
#define G1E 16                // edges per gemm1 block

typedef __attribute__((ext_vector_type(8))) short bf16x8;
typedef __attribute__((ext_vector_type(4))) float f32x4;

#define AS1 __attribute__((address_space(1)))
#define AS3 __attribute__((address_space(3)))

__device__ __forceinline__ float bf2f(unsigned short u) {
  union { unsigned int i; float f; } v; v.i = ((unsigned int)u) << 16; return v.f;
}
__device__ __forceinline__ unsigned short f2bf(float f) {
  union { float f; unsigned int i; } v; v.f = f;
  return (unsigned short)((v.i + 0x7FFFu + ((v.i >> 16) & 1u)) >> 16);  // RNE
}

__device__ __forceinline__ void gl_lds16(const void* g, void* lds_base) {
#if __has_builtin(__builtin_amdgcn_global_load_lds)
  __builtin_amdgcn_global_load_lds((const AS1 unsigned int*)g,
                                   (AS3 unsigned int*)lds_base, 16, 0, 0);
#else
  *(uint4*)((char*)lds_base + (threadIdx.x & 63) * 16) = *(const uint4*)g;
#endif
}

// ---------------- weight fp32 -> bf16 transpose: out[n][k] = in[k][n] ----------------
__global__ void convert_transpose_kernel(const float* __restrict__ in,
                                         unsigned short* __restrict__ out,
                                         int K, int N) {
  long long idx = (long long)blockIdx.x * blockDim.x + threadIdx.x;
  if (idx >= (long long)K * N) return;
  int k = (int)(idx % K);
  int n = (int)(idx / K);
  out[idx] = f2bf(in[(long long)k * N + n]);
}

// -------- kp3 build, v2: COALESCED READS (linear over k3w), scattered 2B writes ------
// Writes merge in L2 (kp3 8.4 MB stays resident during the build). Inverse mapping of:
// kp3[(((o*32+rt)*2+hh)*2+chalf)*512 + lane*8 + j] = bf16(k3w[r*4096 + c*64 + o]),
// r = rt*32+hh*16+(lane&15), c = chalf*32+(lane>>4)*8+j.
__global__ void build_kpt3_kernel(const float* __restrict__ k3w,
                                  unsigned short* __restrict__ kp3) {
  int idx = blockIdx.x * blockDim.x + threadIdx.x;  // linear over k3w (r*4096 + c*64 + o)
  if (idx >= (64 << 16)) return;
  int o = idx & 63;
  int c = (idx >> 6) & 63;
  int r = idx >> 12;
  int rt = r >> 5, hh = (r >> 4) & 1, l15r = r & 15;
  int chalf = c >> 5, lane_hi = (c >> 3) & 3, j = c & 7;
  int lane = lane_hi * 16 + l15r;
  kp3[(size_t)((((o * 32 + rt) * 2 + hh) * 2 + chalf) * 512) + lane * 8 + j] =
      f2bf(k3w[idx]);
}

// --------- gemm1 v2: 16 edges per block; k1w tile in registers reused 16x ----------
// e1 row p (src-sorted order) = relu(ea[sid[p]] @ k1_w + k1_b), bf16 out.
__global__ void gemm1_kernel(const float* __restrict__ ea, const float* __restrict__ k1w,
                             const float* __restrict__ k1b, const int* __restrict__ sid,
                             unsigned short* __restrict__ e1c, int e0, int E) {
  __shared__ float af[G1E][6];
  int t = threadIdx.x;
  int p0 = e0 + blockIdx.x * G1E;
  if (t < G1E * 6) {
    int le = t / 6, j = t - le * 6;
    int p = p0 + le;
    int e = (p < E) ? (sid ? sid[p] : p) : -1;
    af[le][j] = (e >= 0) ? ea[(long long)e * 6 + j] : 0.0f;
  }
  __syncthreads();
  int c4 = t * 4;
  float4 b4 = *(const float4*)&k1b[c4];
  float4 w[6];
#pragma unroll
  for (int j = 0; j < 6; j++) w[j] = *(const float4*)&k1w[j * KW + c4];
#pragma unroll 4
  for (int le = 0; le < G1E; le++) {
    float a0 = b4.x, a1 = b4.y, a2 = b4.z, a3 = b4.w;
#pragma unroll
    for (int j = 0; j < 6; j++) {
      float av = af[le][j];  // LDS broadcast (same addr all lanes)
      a0 += av * w[j].x; a1 += av * w[j].y; a2 += av * w[j].z; a3 += av * w[j].w;
    }
    ushort4 o;
    o.x = f2bf(fmaxf(a0, 0.f)); o.y = f2bf(fmaxf(a1, 0.f));
    o.z = f2bf(fmaxf(a2, 0.f)); o.w = f2bf(fmaxf(a3, 0.f));
    *(ushort4*)&e1c[(long long)(blockIdx.x * G1E + le) * KW + c4] = o;
  }
}

// ------- bf16 GEMM: C = A @ BT^T + bias, opt relu ---------------------------------
// kblocked: write C in K-blocked layout C[(n>>5)*E_PAD + (row0+m)][n&31], rows
// contiguous (input already src-sorted).
__global__ __launch_bounds__(256, 2)
void gemm_bt_kernel(const unsigned short* __restrict__ A,
                    const unsigned short* __restrict__ BT,
                    const float* __restrict__ bias,
                    unsigned short* __restrict__ C,
                    int row0, int N, int K, int mtiles, int do_relu, int kblocked) {
  __shared__ unsigned short sA[128 * 64];
  __shared__ unsigned short sB[128 * 64];
  const int tid  = threadIdx.x;
  const int wave = tid >> 6;
  const int lane = tid & 63;
  const int mt = blockIdx.x % mtiles;
  const int nt = blockIdx.x / mtiles;
  const long long m0 = (long long)mt * 128;
  const int n0 = nt * 128;
  const int wm = wave >> 1, wn = wave & 1;
  const int l15 = lane & 15, quad = lane >> 4;

  f32x4 acc[4][4];
#pragma unroll
  for (int i = 0; i < 4; i++)
#pragma unroll
    for (int j = 0; j < 4; j++) { f32x4 z = {0.f, 0.f, 0.f, 0.f}; acc[i][j] = z; }

  int a_off[4][2], b_off[4][2];
#pragma unroll
  for (int i = 0; i < 4; i++) {
    int ra = wm * 64 + i * 16 + l15;
    int rb = wn * 64 + i * 16 + l15;
#pragma unroll
    for (int kk = 0; kk < 2; kk++) {
      int q = kk * 4 + quad;
      a_off[i][kk] = (ra * 8 + (q ^ (ra & 7))) * 16;
      b_off[i][kk] = (rb * 8 + (q ^ (rb & 7))) * 16;
    }
  }

  int st_row[4], st_q[4];
#pragma unroll
  for (int t = 0; t < 4; t++) {
    int p = (wave * 4 + t) * 64 + lane;
    st_row[t] = p >> 3;
    st_q[t] = (p & 7) ^ ((p >> 3) & 7);
  }

  for (int k0 = 0; k0 < K; k0 += 64) {
    __syncthreads();
#pragma unroll
    for (int t = 0; t < 4; t++) {
      const unsigned short* ga = A + (m0 + st_row[t]) * K + (k0 + st_q[t] * 8);
      const unsigned short* gb = BT + ((long long)(n0 + st_row[t])) * K + (k0 + st_q[t] * 8);
      gl_lds16(ga, (void*)&sA[(wave * 4 + t) * 64 * 8]);
      gl_lds16(gb, (void*)&sB[(wave * 4 + t) * 64 * 8]);
    }
    __syncthreads();

#pragma unroll
    for (int kk = 0; kk < 2; kk++) {
      bf16x8 af[4], bfr[4];
#pragma unroll
      for (int i = 0; i < 4; i++) af[i]  = *(const bf16x8*)((const char*)sA + a_off[i][kk]);
#pragma unroll
      for (int i = 0; i < 4; i++) bfr[i] = *(const bf16x8*)((const char*)sB + b_off[i][kk]);
#pragma unroll
      for (int mi = 0; mi < 4; mi++)
#pragma unroll
        for (int ni = 0; ni < 4; ni++)
          acc[mi][ni] = __builtin_amdgcn_mfma_f32_16x16x32_bf16(af[mi], bfr[ni], acc[mi][ni], 0, 0, 0);
    }
  }

  float bias_v[4];
#pragma unroll
  for (int ni = 0; ni < 4; ni++) bias_v[ni] = bias[n0 + wn * 64 + ni * 16 + l15];
#pragma unroll
  for (int mi = 0; mi < 4; mi++) {
#pragma unroll
    for (int ni = 0; ni < 4; ni++) {
#pragma unroll
      for (int r = 0; r < 4; r++) {
        long long m = m0 + wm * 64 + mi * 16 + quad * 4 + r;
        int n = n0 + wn * 64 + ni * 16 + l15;
        float v = acc[mi][ni][r] + bias_v[ni];
        if (do_relu) v = fmaxf(v, 0.f);
        if (kblocked)
          C[((long long)(n >> 5) * E_PAD + (row0 + m)) * 32 + (n & 31)] = f2bf(v);
        else
          C[m * N + n] = f2bf(v);
      }
    }
  }
}

// ---------------- degree (by dst, fp32) ----------------
__global__ void deg_kernel(const int* __restrict__ dst, float* __restrict__ deg, int E) {
  int e = blockIdx.x * blockDim.x + threadIdx.x;
  if (e < E) atomicAdd(&deg[dst[e]], 1.0f);
}

// ---------------- counting sort (generic by key array) ----------------
__global__ void count_kernel(const int* __restrict__ key, int* __restrict__ cnt, int E) {
  int e = blockIdx.x * blockDim.x + threadIdx.x;
  if (e < E) atomicAdd(&cnt[key[e]], 1);
}

__global__ void scan_kernel(const int* __restrict__ cnt, int* __restrict__ start,
                            int* __restrict__ cursor) {
  __shared__ int psum[1024];
  int t = threadIdx.x;
  int s0 = t * 10;
  int vals[10];
  int local = 0;
#pragma unroll
  for (int i = 0; i < 10; i++) {
    int idx = s0 + i;
    vals[i] = (idx < NN) ? cnt[idx] : 0;
    local += vals[i];
  }
  psum[t] = local;
  __syncthreads();
  for (int off = 1; off < 1024; off <<= 1) {
    int v = (t >= off) ? psum[t - off] : 0;
    __syncthreads();
    psum[t] += v;
    __syncthreads();
  }
  int excl = psum[t] - local;
#pragma unroll
  for (int i = 0; i < 10; i++) {
    int idx = s0 + i;
    if (idx < NN) { start[idx] = excl; cursor[idx] = excl; excl += vals[i]; }
  }
  if (t == 0) start[NN] = NE;
}

// scatter by src; also records pose[e] = src-sorted position of edge e
__global__ void scatter_kernel(const int* __restrict__ src, int* __restrict__ cursor,
                               int* __restrict__ sorted_eid, int* __restrict__ pose, int E) {
  int e = blockIdx.x * blockDim.x + threadIdx.x;
  if (e < E) {
    int pos = atomicAdd(&cursor[src[e]], 1);
    sorted_eid[pos] = e;
    pose[e] = pos;
  }
}

// scatter by dst storing src-sorted positions: dst-CSR of msg rows
__global__ void scatter2_kernel(const int* __restrict__ dst, int* __restrict__ cursor2,
                                const int* __restrict__ pose, int* __restrict__ sid2, int E) {
  int e = blockIdx.x * blockDim.x + threadIdx.x;
  if (e < E) {
    int pos = atomicAdd(&cursor2[dst[e]], 1);
    sid2[pos] = pose[e];
  }
}

// ---------------- per-(group,wave) static tile lists: topology-only, built once -------
__global__ void build_tiles_kernel(const int* __restrict__ start, int2* __restrict__ tiles) {
  int g = blockIdx.x * blockDim.x + threadIdx.x;
  if (g >= NGRP2) return;
  int nt[4] = {0, 0, 0, 0};
  for (int w = 0; w < 4; w++)
    for (int s = 0; s < MAXSETS; s++)
      tiles[(g * 4 + w) * MAXSETS + s] = make_int2(0, 0);
  int t = 0;
  for (int i = 0; i < GNODES; i++) {
    int na = g * GNODES + i;
    int nb = na + 1;
    if (na > NN) na = NN;
    if (nb > NN) nb = NN;
    int s = start[na], e = start[nb];
    for (int m0 = s; m0 < e; m0 += 16) {
      int w = t & 3;
      if (nt[w] < MAXSETS) {
        int c = e - m0; if (c > 16) c = 16;
        tiles[(g * 4 + w) * MAXSETS + nt[w]] = make_int2(i | (c << 16), m0);
        nt[w]++;
      }
      t++;
    }
  }
}

// ---------------- h0 (+ bf16 copy + msg-bias) ----------------
__global__ void h0_mb_kernel(const float* __restrict__ x, const float* __restrict__ fc1w,
                             const float* __restrict__ fc1b, const float* __restrict__ k3b,
                             float* __restrict__ h, unsigned short* __restrict__ hbf,
                             float* __restrict__ mb) {
  int wave = threadIdx.x >> 6, lane = threadIdx.x & 63;
  int n = blockIdx.x * 4 + wave;
  if (n >= NN) return;
  float v = x[n] * fc1w[lane] + fc1b[lane];
  h[n * 64 + lane] = v;
  hbf[n * 64 + lane] = f2bf(v);
  float mbv = 0.f;
#pragma unroll
  for (int c = 0; c < 64; c++)
    mbv += __shfl(v, c, 64) * k3b[c * 64 + lane];
  mb[n * 64 + lane] = mbv;
}

// ---------------- fused per-depth message kernel (d-trick, FROZEN v12 structure) -----
// Best measured: ~378 us. Single 32 KB slab, 2 barriers/rt, e2p prefetch after
// barrier-1 overlapping produce; coalesced kp3 + e2p 1 KB wave-loads.
// launch_bounds(256,3): 84 VGPR, NO SPILLS. (256,4) -> 64-VGPR step + scratch
// spills (+500 MB WRITE, 2x dur) — measured round 13. DO NOT CHANGE.
__global__ __launch_bounds__(256, 3)
void fused_msg_kernel(const unsigned short* __restrict__ hbf,
                      const unsigned short* __restrict__ e2p,
                      const unsigned short* __restrict__ kp3,
                      const int2* __restrict__ tiles,
                      const int* __restrict__ sorted_eid,
                      const int* __restrict__ dst,
                      const float* __restrict__ mb,
                      float* __restrict__ agg,
                      unsigned short* __restrict__ msgh,
                      float* __restrict__ msgf,
                      int msg_mode) {
  __shared__ unsigned short slab[GNODES * 512];  // 32 nodes x 16 o x 32 r = 32 KB
  const int tid = threadIdx.x, wave = tid >> 6, lane = tid & 63;
  const int l15 = lane & 15, quad = lane >> 4;
  const int oh = blockIdx.x & 3;           // XCD-pinned o-quarter
  const int ng = blockIdx.x >> 2;
  const int n0 = ng * GNODES;

  // ---- load static slots ----
  int s_node[MAXSETS], s_j[MAXSETS], s_cnt[MAXSETS], row_off[MAXSETS];
  const int2* tp = tiles + (ng * 4 + wave) * MAXSETS;
#pragma unroll
  for (int s2 = 0; s2 < MAXSETS; s2++) {
    int2 rec = tp[s2];
    s_node[s2] = rec.x & 0xffff;
    s_cnt[s2]  = rec.x >> 16;
    s_j[s2]    = rec.y;
    int c = s_cnt[s2];
    int sl = (l15 < c) ? l15 : (c > 0 ? c - 1 : 0);
    row_off[s2] = (s_j[s2] + sl) * 32 + quad * 8;  // within an rt-slice of e2p
  }

  f32x4 acc[MAXSETS];
#pragma unroll
  for (int s2 = 0; s2 < MAXSETS; s2++) { f32x4 z = {0.f, 0.f, 0.f, 0.f}; acc[s2] = z; }

  // producer B-frags (n = node), two 16-node halves, loop-invariant
  bf16x8 pb0[2], pb1[2];
#pragma unroll
  for (int g2 = 0; g2 < 2; g2++) {
    pb0[g2] = *(const bf16x8*)(hbf + (n0 + g2 * 16 + l15) * 64 + quad * 8);
    pb1[g2] = *(const bf16x8*)(hbf + (n0 + g2 * 16 + l15) * 64 + 32 + quad * 8);
  }

  for (int rt = 0; rt < 32; rt++) {
    __syncthreads();  // WAR: prev consume done before overwrite
    // prefetch consumer e2p frags (coalesced 1 KB wave-loads; overlap produce)
    const unsigned short* e2s = e2p + (size_t)rt * (E_PAD * 32);
    bf16x8 apre[MAXSETS];
#pragma unroll
    for (int s2 = 0; s2 < MAXSETS; s2++) {
      if (s_cnt[s2])  // wave-uniform
        apre[s2] = *(const bf16x8*)(e2s + row_off[s2]);
    }
    // ---- produce: 32 m-tiles (o_loc 16 x hh 2), wave covers 8, coalesced kp3 ----
#pragma unroll 4
    for (int u = 0; u < 8; u++) {
      int id = wave * 8 + u;
      int o_loc = id >> 1, hh = id & 1;
      int o = oh * 16 + o_loc;
      const unsigned short* blk = kp3 + (size_t)(((o * 32 + rt) * 2 + hh) * 2) * 512;
      bf16x8 a0 = *(const bf16x8*)(blk + lane * 8);          // chalf 0
      bf16x8 a1 = *(const bf16x8*)(blk + 512 + lane * 8);    // chalf 1
      int chunk_log = o_loc * 4 + hh * 2 + (quad >> 1);
      int phys = chunk_log ^ (l15 & 7);
#pragma unroll
      for (int g2 = 0; g2 < 2; g2++) {
        f32x4 c = {0.f, 0.f, 0.f, 0.f};
        c = __builtin_amdgcn_mfma_f32_16x16x32_bf16(a0, pb0[g2], c, 0, 0, 0);
        c = __builtin_amdgcn_mfma_f32_16x16x32_bf16(a1, pb1[g2], c, 0, 0, 0);
        // lane: node = g2*16 + l15, r_loc = hh*16 + quad*4 + reg -> one b64
        unsigned int w0 = (unsigned int)f2bf(c[0]) | ((unsigned int)f2bf(c[1]) << 16);
        unsigned int w1 = (unsigned int)f2bf(c[2]) | ((unsigned int)f2bf(c[3]) << 16);
        uint2* p = (uint2*)((char*)slab + (g2 * 16 + l15) * 1024 + phys * 16 + (quad & 1) * 8);
        uint2 w; w.x = w0; w.y = w1;
        *p = w;
      }
    }
    __syncthreads();  // RAW: slab ready
    // ---- consume: static slots, one k=32 MFMA each ----
#pragma unroll
    for (int s2 = 0; s2 < MAXSETS; s2++) {
      if (s_cnt[s2] == 0) continue;  // wave-uniform
      int node = s_node[s2];
      const char* nb = (const char*)slab + node * 1024;
      bf16x8 b = *(const bf16x8*)(nb + (((l15 * 4 + quad) ^ (node & 7)) * 16));
      acc[s2] = __builtin_amdgcn_mfma_f32_16x16x32_bf16(apre[s2], b, acc[s2], 0, 0, 0);
    }
  }

  // ---- epilogue (static slots), o-quarter slice ----
#pragma unroll
  for (int s2 = 0; s2 < MAXSETS; s2++) {
    if (s_cnt[s2] == 0) continue;  // wave-uniform
    float mbv = mb[(n0 + s_node[s2]) * 64 + oh * 16 + l15];
#pragma unroll
    for (int reg = 0; reg < 4; reg++) {
      int mloc = quad * 4 + reg;
      if (mloc < s_cnt[s2]) {
        int p = s_j[s2] + mloc;  // src-sorted position
        float v = acc[s2][reg] + mbv;
        if (msg_mode == 2) {
          __builtin_nontemporal_store(v, &msgf[p * 64 + oh * 16 + l15]);
        } else if (msg_mode == 1) {
          __builtin_nontemporal_store(f2bf(v), &msgh[p * 64 + oh * 16 + l15]);
        } else {
          int d = dst[sorted_eid[p]];
          atomicAdd(&agg[d * 64 + oh * 16 + l15], v);
        }
      }
    }
  }
}

// -------- gather msg rows by dst-CSR + full node update (+hbf/mb for next depth) --------
__global__ void scatter_update_mb_kernel(const unsigned short* __restrict__ msgh,
                                         const float* __restrict__ msgf,
                                         const int* __restrict__ startd,
                                         const int* __restrict__ sid2,
                                         const float* __restrict__ h,
                                         const float* __restrict__ root,
                                         const float* __restrict__ convb,
                                         const float* __restrict__ k3b,
                                         float* __restrict__ hout,
                                         unsigned short* __restrict__ hbf,
                                         float* __restrict__ mb,
                                         int do_relu, int msg_mode) {
  int wave = threadIdx.x >> 6, lane = threadIdx.x & 63;
  int n = blockIdx.x * 4 + wave;
  if (n >= NN) return;
  float hv = h[n * 64 + lane];
  float racc = 0.f;
#pragma unroll
  for (int c = 0; c < 64; c++)
    racc += __shfl(hv, c, 64) * root[c * 64 + lane];
  int js = startd[n], je = startd[n + 1];
  float sum = 0.f;
  if (msg_mode == 2) {
    for (int j = js; j < je; j++) { int p = sid2[j]; sum += msgf[p * 64 + lane]; }
  } else {
    for (int j = js; j < je; j++) { int p = sid2[j]; sum += bf2f(msgh[p * 64 + lane]); }
  }
  float inv = (je > js) ? 1.0f / (float)(je - js) : 0.f;
  float v = sum * inv + racc + convb[lane];
  if (do_relu) v = fmaxf(v, 0.f);
  hout[n * 64 + lane] = v;
  hbf[n * 64 + lane] = f2bf(v);
  float mbv = 0.f;
#pragma unroll
  for (int c = 0; c < 64; c++)
    mbv += __shfl(v, c, 64) * k3b[c * 64 + lane];
  mb[n * 64 + lane] = mbv;
}

// -------- update (+ bf16 copy + msg-bias), atomic-agg variant --------
__global__ void update_mb_kernel(const float* __restrict__ h, const float* __restrict__ agg,
                                 const float* __restrict__ deg, const float* __restrict__ root,
                                 const float* __restrict__ convb, const float* __restrict__ k3b,
                                 float* __restrict__ hout, unsigned short* __restrict__ hbf,
                                 float* __restrict__ mb, int do_relu) {
  int wave = threadIdx.x >> 6, lane = threadIdx.x & 63;
  int n = blockIdx.x * 4 + wave;
  if (n >= NN) return;
  float hv = h[n * 64 + lane];
  float acc = 0.f;
#pragma unroll
  for (int c = 0; c < 64; c++)
    acc += __shfl(hv, c, 64) * root[c * 64 + lane];
  float dg = deg[n];
  float inv = dg > 0.f ? 1.0f / dg : 0.f;
  float v = agg[n * 64 + lane] * inv + acc + convb[lane];
  if (do_relu) v = fmaxf(v, 0.f);
  hout[n * 64 + lane] = v;
  hbf[n * 64 + lane] = f2bf(v);
  float mbv = 0.f;
#pragma unroll
  for (int c = 0; c < 64; c++)
    mbv += __shfl(v, c, 64) * k3b[c * 64 + lane];
  mb[n * 64 + lane] = mbv;
}

// ---------------- fallback-path kernels (round-2 Plan C, proven) ----------------
__global__ void h0_kernel(const float* __restrict__ x, const float* __restrict__ fc1w,
                          const float* __restrict__ fc1b, float* __restrict__ h) {
  int idx = blockIdx.x * blockDim.x + threadIdx.x;
  if (idx >= NN * WIDTH) return;
  int n = idx >> 6, w = idx & 63;
  h[idx] = x[n] * fc1w[w] + fc1b[w];
}

__global__ void msg_kernel(const float* __restrict__ h, const unsigned short* __restrict__ Wc,
                           const int* __restrict__ src, const int* __restrict__ dst,
                           float* __restrict__ agg, int e0, int e_end) {
  int wave = threadIdx.x >> 6;
  int lane = threadIdx.x & 63;
  int e = e0 + blockIdx.x * 4 + wave;
  if (e >= e_end) return;
  int s = src[e], d = dst[e];
  float hv = h[s * WIDTH + lane];
  const unsigned short* We = Wc + (long long)(e - e0) * 4096;
  float acc = 0.f;
#pragma unroll
  for (int c = 0; c < 64; c++) {
    float hs = __shfl(hv, c, 64);
    acc += hs * bf2f(We[c * 64 + lane]);
  }
  atomicAdd(&agg[d * WIDTH + lane], acc);
}

__global__ void update_kernel(const float* __restrict__ h, const float* __restrict__ agg,
                              const float* __restrict__ deg, const float* __restrict__ root,
                              const float* __restrict__ convb, float* __restrict__ hout,
                              int do_relu) {
  int wave = threadIdx.x >> 6, lane = threadIdx.x & 63;
  int n = blockIdx.x * 4 + wave;
  if (n >= NN) return;
  float hv = h[n * WIDTH + lane];
  float acc = 0.f;
#pragma unroll
  for (int c = 0; c < 64; c++)
    acc += __shfl(hv, c, 64) * root[c * WIDTH + lane];
  float dg = deg[n];
  float inv = dg > 0.f ? 1.0f / dg : 0.f;
  float v = agg[n * WIDTH + lane] * inv + acc + convb[lane];
  if (do_relu) v = fmaxf(v, 0.f);
  hout[n * WIDTH + lane] = v;
}

__global__ void fc2_kernel(const float* __restrict__ h, const float* __restrict__ fc2w,
                           const float* __restrict__ fc2b, float* __restrict__ out) {
  int wave = threadIdx.x >> 6, lane = threadIdx.x & 63;
  int n = blockIdx.x * 4 + wave;
  if (n >= NN) return;
  float v = h[n * WIDTH + lane] * fc2w[lane];
#pragma unroll
  for (int off = 32; off > 0; off >>= 1) v += __shfl_down(v, off, 64);
  if (lane == 0) out[n] = v + fc2b[0];
}

extern "C" void kernel_launch(void* const* d_in, const int* in_sizes, int n_in,
                              void* d_out, int out_size, void* d_ws, size_t ws_size,
                              hipStream_t stream) {
  const float* x     = (const float*)d_in[0];
  const int*   ei    = (const int*)d_in[1];
  const float* ea    = (const float*)d_in[2];
  const float* fc1w  = (const float*)d_in[3];
  const float* fc1b  = (const float*)d_in[4];
  const float* k1w   = (const float*)d_in[5];
  const float* k1b   = (const float*)d_in[6];
  const float* k2w   = (const float*)d_in[7];
  const float* k2b   = (const float*)d_in[8];
  const float* k3w   = (const float*)d_in[9];
  const float* k3b   = (const float*)d_in[10];
  const float* root  = (const float*)d_in[11];
  const float* convb = (const float*)d_in[12];
  const float* fc2w  = (const float*)d_in[13];
  const float* fc2b  = (const float*)d_in[14];
  float* out = (float*)d_out;
  const int* src = ei;
  const int* dst = ei + NE;

  char* ws = (char*)d_ws;
  size_t off = 0;
  auto alloc = [&](size_t bytes) -> char* {
    char* p = ws + off; off = (off + bytes + 255) & ~(size_t)255; return p;
  };
  auto al = [](size_t x) { return (x + 255) & ~(size_t)255; };

  // ---- common ----
  unsigned short* k2wT = (unsigned short*)alloc((size_t)KW * KW * 2);
  float* ha  = (float*)alloc((size_t)NN * WIDTH * 4);
  float* hb  = (float*)alloc((size_t)NN * WIDTH * 4);
  float* agg = (float*)alloc((size_t)NN * WIDTH * 4);
  float* deg = (float*)alloc((size_t)NN * 4);
  if (ws_size < off + 4096) return;

  const size_t PT_CH = 128 * KW * 2;  // 262144

  size_t sz_kpt  = (size_t)(64 << 16) * 2;     // kp3: 8.39 MB
  size_t sz_mb   = (size_t)NN * 64 * 4;
  size_t sz_hbf  = (size_t)NN_PAD * 64 * 2;
  size_t sz_cnt  = (size_t)NN * 4;
  size_t sz_st   = (size_t)(NN + 1) * 4;
  size_t sz_sid  = (size_t)NE * 4;
  size_t sz_e2   = (size_t)E_PAD * KW * 2;     // e2p
  size_t sz_tiles = (size_t)NGRP2 * 4 * MAXSETS * 8;

  size_t core = al(sz_kpt) + al(sz_mb) + al(sz_hbf) + al(sz_cnt) + al(sz_st) + al(sz_cnt)
              + al(sz_sid) + al(sz_e2) + al(sz_tiles) + al(sz_sid) /*pose*/;
  size_t msg_csr = al(sz_cnt) + al(sz_st) + al(sz_cnt) + al(sz_sid);
  size_t e1c_min = al((size_t)8 * PT_CH);

  int msg_mode;  // 2 = fp32 msg buffer, 1 = bf16 msg buffer, 0 = atomic agg, -1 = Plan C
  if (ws_size >= off + core + msg_csr + al((size_t)NE * 64 * 4) + e1c_min)       msg_mode = 2;
  else if (ws_size >= off + core + msg_csr + al((size_t)NE * 64 * 2) + e1c_min)  msg_mode = 1;
  else if (ws_size >= off + core + e1c_min + 8192)                               msg_mode = 0;
  else                                                                           msg_mode = -1;

  if (msg_mode >= 0) {
    // ================= FUSED d-TRICK PATH (v14 = v13 + coalesced kp3 build) =========
    unsigned short* kp3 = (unsigned short*)alloc(sz_kpt);
    float* mb   = (float*)alloc(sz_mb);
    unsigned short* hbf = (unsigned short*)alloc(sz_hbf);
    int* cnt    = (int*)alloc(sz_cnt);
    int* starta = (int*)alloc(sz_st);
    int* cursor = (int*)alloc(sz_cnt);
    int* sid    = (int*)alloc(sz_sid);
    unsigned short* e2p = (unsigned short*)alloc(sz_e2);
    int2* tiles = (int2*)alloc(sz_tiles);
    int* pose   = (int*)alloc(sz_sid);
    int* cnt2 = nullptr; int* startd = nullptr;
    int* cursor2 = nullptr; int* sid2 = nullptr;
    unsigned short* msgh = nullptr; float* msgf = nullptr;
    if (msg_mode >= 1) {
      cnt2    = (int*)alloc(sz_cnt);
      startd  = (int*)alloc(sz_st);
      cursor2 = (int*)alloc(sz_cnt);
      sid2    = (int*)alloc(sz_sid);
      if (msg_mode == 2) msgf = (float*)alloc((size_t)NE * 64 * 4);
      else               msgh = (unsigned short*)alloc((size_t)NE * 64 * 2);
    }
    size_t left = ws_size - off;
    int TC = (int)(left / PT_CH); if (TC > MT_ALL) TC = MT_ALL;
    unsigned short* e1c = (unsigned short*)alloc((size_t)TC * PT_CH);

    convert_transpose_kernel<<<(KW * KW) / 256, 256, 0, stream>>>(k2w, k2wT, KW, KW);
    build_kpt3_kernel<<<(64 << 16) / 256, 256, 0, stream>>>(k3w, kp3);
    hipMemsetAsync(cnt, 0, sz_cnt, stream);
    count_kernel<<<(NE + 255) / 256, 256, 0, stream>>>(src, cnt, NE);
    scan_kernel<<<1, 1024, 0, stream>>>(cnt, starta, cursor);
    scatter_kernel<<<(NE + 255) / 256, 256, 0, stream>>>(src, cursor, sid, pose, NE);
    build_tiles_kernel<<<(NGRP2 + 255) / 256, 256, 0, stream>>>(starta, tiles);
    if (msg_mode >= 1) {
      hipMemsetAsync(cnt2, 0, sz_cnt, stream);
      count_kernel<<<(NE + 255) / 256, 256, 0, stream>>>(dst, cnt2, NE);
      scan_kernel<<<1, 1024, 0, stream>>>(cnt2, startd, cursor2);
      scatter2_kernel<<<(NE + 255) / 256, 256, 0, stream>>>(dst, cursor2, pose, sid2, NE);
    } else {
      hipMemsetAsync(deg, 0, (size_t)NN * 4, stream);
      deg_kernel<<<(NE + 255) / 256, 256, 0, stream>>>(dst, deg, NE);
    }
    h0_mb_kernel<<<(NN + 3) / 4, 256, 0, stream>>>(x, fc1w, fc1b, k3b, ha, hbf, mb);
    // e1 gathered via sid (sorted order) -> gemm2 writes e2p contiguously
    for (int t0 = 0; t0 < MT_ALL; t0 += TC) {
      int tc = (MT_ALL - t0 < TC) ? (MT_ALL - t0) : TC;
      gemm1_kernel<<<tc * 128 / G1E, 256, 0, stream>>>(ea, k1w, k1b, sid, e1c, t0 * 128, NE);
      gemm_bt_kernel<<<tc * (KW / 128), 256, 0, stream>>>(
          e1c, k2wT, k2b, e2p, t0 * 128, KW, KW, tc, 1, 1);
    }
    float* hc = ha; float* hn = hb;
    for (int k = 0; k < DEPTH; k++) {
      if (msg_mode == 0) hipMemsetAsync(agg, 0, (size_t)NN * WIDTH * 4, stream);
      fused_msg_kernel<<<4 * NGRP2, 256, 0, stream>>>(
          hbf, e2p, kp3, tiles, sid, dst, mb, agg, msgh, msgf, msg_mode);
      if (msg_mode >= 1)
        scatter_update_mb_kernel<<<(NN + 3) / 4, 256, 0, stream>>>(
            msgh, msgf, startd, sid2, hc, root, convb, k3b, hn, hbf, mb,
            (k != DEPTH - 1) ? 1 : 0, msg_mode);
      else
        update_mb_kernel<<<(NN + 3) / 4, 256, 0, stream>>>(
            hc, agg, deg, root, convb, k3b, hn, hbf, mb, (k != DEPTH - 1) ? 1 : 0);
      float* t = hc; hc = hn; hn = t;
    }
    fc2_kernel<<<(NN + 3) / 4, 256, 0, stream>>>(hc, fc2w, fc2b, out);
  } else {
    // ================= FALLBACK: round-2 Plan C (proven) =================
    unsigned short* k3wT = (unsigned short*)alloc((size_t)4096 * KW * 2);
    size_t rem = (ws_size > off) ? ws_size - off : 0;
    const size_t PT_W = 128 * 4096 * 2;
    size_t per_tile = 2 * PT_CH + PT_W;
    long long tcl = (long long)(rem / per_tile);
    int TC = (tcl > 98) ? 98 : (int)tcl;
    if (TC < 1) return;
    unsigned short* e1c = (unsigned short*)alloc((size_t)TC * PT_CH);
    unsigned short* e2c = (unsigned short*)alloc((size_t)TC * PT_CH);
    unsigned short* Wc  = (unsigned short*)alloc((size_t)TC * PT_W);

    convert_transpose_kernel<<<(KW * KW) / 256, 256, 0, stream>>>(k2w, k2wT, KW, KW);
    convert_transpose_kernel<<<(KW * 4096) / 256, 256, 0, stream>>>(k3w, k3wT, KW, 4096);
    hipMemsetAsync(deg, 0, (size_t)NN * 4, stream);
    deg_kernel<<<(NE + 255) / 256, 256, 0, stream>>>(dst, deg, NE);
    h0_kernel<<<(NN * WIDTH) / 256, 256, 0, stream>>>(x, fc1w, fc1b, ha);

    float* hc = ha; float* hn = hb;
    for (int k = 0; k < DEPTH; k++) {
      hipMemsetAsync(agg, 0, (size_t)NN * WIDTH * 4, stream);
      for (int t0 = 0; t0 < MT_ALL; t0 += TC) {
        int tc = (MT_ALL - t0 < TC) ? (MT_ALL - t0) : TC;
        gemm1_kernel<<<tc * 128 / G1E, 256, 0, stream>>>(ea, k1w, k1b, nullptr, e1c,
                                                         t0 * 128, NE);
        gemm_bt_kernel<<<tc * (KW / 128), 256, 0, stream>>>(e1c, k2wT, k2b, e2c,
                                                            0, KW, KW, tc, 1, 0);
        gemm_bt_kernel<<<tc * (4096 / 128), 256, 0, stream>>>(e2c, k3wT, k3b, Wc,
                                                              0, 4096, KW, tc, 0, 0);
        int e0 = t0 * 128;
        int e_end = (t0 + tc) * 128; if (e_end > NE) e_end = NE;
        if (e_end > e0)
          msg_kernel<<<(e_end - e0 + 3) / 4, 256, 0, stream>>>(hc, Wc, src, dst, agg, e0, e_end);
      }
      update_kernel<<<(NN + 3) / 4, 256, 0, stream>>>(hc, agg, deg, root, convb, hn,
                                                      (k != DEPTH - 1) ? 1 : 0);
      float* t = hc; hc = hn; hn = t;
    }
    fc2_kernel<<<(NN + 3) / 4, 256, 0, stream>>>(hc, fc2w, fc2b, out);
  }
}

// Round 17
// 3948.796 us; speedup vs baseline: 1.5519x; 1.0182x over previous
//
#include <hip/hip_runtime.h>
#include <hip/hip_bf16.h>

#define WIDTH 64
#define KW 1024
#define DEPTH 6
#define NN 10000
#define NE 100000
#define E_PAD 100096          // 782 * 128
#define MT_ALL (E_PAD / 128)  // 782 M-tiles
#define GNODES 32
#define MAXSETS 12
#define NGRP2 313             // ceil(NN / GNODES)
#define NN_PAD (NGRP2 * GNODES)  // 10016
#define G1E 16                // edges per gemm1 block

typedef __attribute__((ext_vector_type(8))) short bf16x8;
typedef __attribute__((ext_vector_type(4))) float f32x4;

#define AS1 __attribute__((address_space(1)))
#define AS3 __attribute__((address_space(3)))

__device__ __forceinline__ float bf2f(unsigned short u) {
  union { unsigned int i; float f; } v; v.i = ((unsigned int)u) << 16; return v.f;
}
__device__ __forceinline__ unsigned short f2bf(float f) {
  union { float f; unsigned int i; } v; v.f = f;
  return (unsigned short)((v.i + 0x7FFFu + ((v.i >> 16) & 1u)) >> 16);  // RNE
}

__device__ __forceinline__ void gl_lds16(const void* g, void* lds_base) {
#if __has_builtin(__builtin_amdgcn_global_load_lds)
  __builtin_amdgcn_global_load_lds((const AS1 unsigned int*)g,
                                   (AS3 unsigned int*)lds_base, 16, 0, 0);
#else
  *(uint4*)((char*)lds_base + (threadIdx.x & 63) * 16) = *(const uint4*)g;
#endif
}

// ---------------- weight fp32 -> bf16 transpose: out[n][k] = in[k][n] ----------------
__global__ void convert_transpose_kernel(const float* __restrict__ in,
                                         unsigned short* __restrict__ out,
                                         int K, int N) {
  long long idx = (long long)blockIdx.x * blockDim.x + threadIdx.x;
  if (idx >= (long long)K * N) return;
  int k = (int)(idx % K);
  int n = (int)(idx / K);
  out[idx] = f2bf(in[(long long)k * N + n]);
}

// -------- kp3 build, v2: COALESCED READS (linear over k3w), scattered 2B writes ------
__global__ void build_kpt3_kernel(const float* __restrict__ k3w,
                                  unsigned short* __restrict__ kp3) {
  int idx = blockIdx.x * blockDim.x + threadIdx.x;  // linear over k3w (r*4096 + c*64 + o)
  if (idx >= (64 << 16)) return;
  int o = idx & 63;
  int c = (idx >> 6) & 63;
  int r = idx >> 12;
  int rt = r >> 5, hh = (r >> 4) & 1, l15r = r & 15;
  int chalf = c >> 5, lane_hi = (c >> 3) & 3, j = c & 7;
  int lane = lane_hi * 16 + l15r;
  kp3[(size_t)((((o * 32 + rt) * 2 + hh) * 2 + chalf) * 512) + lane * 8 + j] =
      f2bf(k3w[idx]);
}

// --------- gemm1 v2: 16 edges per block; k1w tile in registers reused 16x ----------
__global__ void gemm1_kernel(const float* __restrict__ ea, const float* __restrict__ k1w,
                             const float* __restrict__ k1b, const int* __restrict__ sid,
                             unsigned short* __restrict__ e1c, int e0, int E) {
  __shared__ float af[G1E][6];
  int t = threadIdx.x;
  int p0 = e0 + blockIdx.x * G1E;
  if (t < G1E * 6) {
    int le = t / 6, j = t - le * 6;
    int p = p0 + le;
    int e = (p < E) ? (sid ? sid[p] : p) : -1;
    af[le][j] = (e >= 0) ? ea[(long long)e * 6 + j] : 0.0f;
  }
  __syncthreads();
  int c4 = t * 4;
  float4 b4 = *(const float4*)&k1b[c4];
  float4 w[6];
#pragma unroll
  for (int j = 0; j < 6; j++) w[j] = *(const float4*)&k1w[j * KW + c4];
#pragma unroll 4
  for (int le = 0; le < G1E; le++) {
    float a0 = b4.x, a1 = b4.y, a2 = b4.z, a3 = b4.w;
#pragma unroll
    for (int j = 0; j < 6; j++) {
      float av = af[le][j];  // LDS broadcast
      a0 += av * w[j].x; a1 += av * w[j].y; a2 += av * w[j].z; a3 += av * w[j].w;
    }
    ushort4 o;
    o.x = f2bf(fmaxf(a0, 0.f)); o.y = f2bf(fmaxf(a1, 0.f));
    o.z = f2bf(fmaxf(a2, 0.f)); o.w = f2bf(fmaxf(a3, 0.f));
    *(ushort4*)&e1c[(long long)(blockIdx.x * G1E + le) * KW + c4] = o;
  }
}

// ------- bf16 GEMM: C = A @ BT^T + bias, opt relu ---------------------------------
__global__ __launch_bounds__(256, 2)
void gemm_bt_kernel(const unsigned short* __restrict__ A,
                    const unsigned short* __restrict__ BT,
                    const float* __restrict__ bias,
                    unsigned short* __restrict__ C,
                    int row0, int N, int K, int mtiles, int do_relu, int kblocked) {
  __shared__ unsigned short sA[128 * 64];
  __shared__ unsigned short sB[128 * 64];
  const int tid  = threadIdx.x;
  const int wave = tid >> 6;
  const int lane = tid & 63;
  const int mt = blockIdx.x % mtiles;
  const int nt = blockIdx.x / mtiles;
  const long long m0 = (long long)mt * 128;
  const int n0 = nt * 128;
  const int wm = wave >> 1, wn = wave & 1;
  const int l15 = lane & 15, quad = lane >> 4;

  f32x4 acc[4][4];
#pragma unroll
  for (int i = 0; i < 4; i++)
#pragma unroll
    for (int j = 0; j < 4; j++) { f32x4 z = {0.f, 0.f, 0.f, 0.f}; acc[i][j] = z; }

  int a_off[4][2], b_off[4][2];
#pragma unroll
  for (int i = 0; i < 4; i++) {
    int ra = wm * 64 + i * 16 + l15;
    int rb = wn * 64 + i * 16 + l15;
#pragma unroll
    for (int kk = 0; kk < 2; kk++) {
      int q = kk * 4 + quad;
      a_off[i][kk] = (ra * 8 + (q ^ (ra & 7))) * 16;
      b_off[i][kk] = (rb * 8 + (q ^ (rb & 7))) * 16;
    }
  }

  int st_row[4], st_q[4];
#pragma unroll
  for (int t = 0; t < 4; t++) {
    int p = (wave * 4 + t) * 64 + lane;
    st_row[t] = p >> 3;
    st_q[t] = (p & 7) ^ ((p >> 3) & 7);
  }

  for (int k0 = 0; k0 < K; k0 += 64) {
    __syncthreads();
#pragma unroll
    for (int t = 0; t < 4; t++) {
      const unsigned short* ga = A + (m0 + st_row[t]) * K + (k0 + st_q[t] * 8);
      const unsigned short* gb = BT + ((long long)(n0 + st_row[t])) * K + (k0 + st_q[t] * 8);
      gl_lds16(ga, (void*)&sA[(wave * 4 + t) * 64 * 8]);
      gl_lds16(gb, (void*)&sB[(wave * 4 + t) * 64 * 8]);
    }
    __syncthreads();

#pragma unroll
    for (int kk = 0; kk < 2; kk++) {
      bf16x8 af[4], bfr[4];
#pragma unroll
      for (int i = 0; i < 4; i++) af[i]  = *(const bf16x8*)((const char*)sA + a_off[i][kk]);
#pragma unroll
      for (int i = 0; i < 4; i++) bfr[i] = *(const bf16x8*)((const char*)sB + b_off[i][kk]);
#pragma unroll
      for (int mi = 0; mi < 4; mi++)
#pragma unroll
        for (int ni = 0; ni < 4; ni++)
          acc[mi][ni] = __builtin_amdgcn_mfma_f32_16x16x32_bf16(af[mi], bfr[ni], acc[mi][ni], 0, 0, 0);
    }
  }

  float bias_v[4];
#pragma unroll
  for (int ni = 0; ni < 4; ni++) bias_v[ni] = bias[n0 + wn * 64 + ni * 16 + l15];
#pragma unroll
  for (int mi = 0; mi < 4; mi++) {
#pragma unroll
    for (int ni = 0; ni < 4; ni++) {
#pragma unroll
      for (int r = 0; r < 4; r++) {
        long long m = m0 + wm * 64 + mi * 16 + quad * 4 + r;
        int n = n0 + wn * 64 + ni * 16 + l15;
        float v = acc[mi][ni][r] + bias_v[ni];
        if (do_relu) v = fmaxf(v, 0.f);
        if (kblocked)
          C[((long long)(n >> 5) * E_PAD + (row0 + m)) * 32 + (n & 31)] = f2bf(v);
        else
          C[m * N + n] = f2bf(v);
      }
    }
  }
}

// ---------------- degree (by dst, fp32) ----------------
__global__ void deg_kernel(const int* __restrict__ dst, float* __restrict__ deg, int E) {
  int e = blockIdx.x * blockDim.x + threadIdx.x;
  if (e < E) atomicAdd(&deg[dst[e]], 1.0f);
}

// ---------------- counting sort (generic by key array) ----------------
__global__ void count_kernel(const int* __restrict__ key, int* __restrict__ cnt, int E) {
  int e = blockIdx.x * blockDim.x + threadIdx.x;
  if (e < E) atomicAdd(&cnt[key[e]], 1);
}

__global__ void scan_kernel(const int* __restrict__ cnt, int* __restrict__ start,
                            int* __restrict__ cursor) {
  __shared__ int psum[1024];
  int t = threadIdx.x;
  int s0 = t * 10;
  int vals[10];
  int local = 0;
#pragma unroll
  for (int i = 0; i < 10; i++) {
    int idx = s0 + i;
    vals[i] = (idx < NN) ? cnt[idx] : 0;
    local += vals[i];
  }
  psum[t] = local;
  __syncthreads();
  for (int off = 1; off < 1024; off <<= 1) {
    int v = (t >= off) ? psum[t - off] : 0;
    __syncthreads();
    psum[t] += v;
    __syncthreads();
  }
  int excl = psum[t] - local;
#pragma unroll
  for (int i = 0; i < 10; i++) {
    int idx = s0 + i;
    if (idx < NN) { start[idx] = excl; cursor[idx] = excl; excl += vals[i]; }
  }
  if (t == 0) start[NN] = NE;
}

// scatter by src; also records pose[e] = src-sorted position of edge e
__global__ void scatter_kernel(const int* __restrict__ src, int* __restrict__ cursor,
                               int* __restrict__ sorted_eid, int* __restrict__ pose, int E) {
  int e = blockIdx.x * blockDim.x + threadIdx.x;
  if (e < E) {
    int pos = atomicAdd(&cursor[src[e]], 1);
    sorted_eid[pos] = e;
    pose[e] = pos;
  }
}

// scatter by dst storing src-sorted positions: dst-CSR of msg rows
__global__ void scatter2_kernel(const int* __restrict__ dst, int* __restrict__ cursor2,
                                const int* __restrict__ pose, int* __restrict__ sid2, int E) {
  int e = blockIdx.x * blockDim.x + threadIdx.x;
  if (e < E) {
    int pos = atomicAdd(&cursor2[dst[e]], 1);
    sid2[pos] = pose[e];
  }
}

// ---------------- per-(group,wave) static tile lists: topology-only, built once -------
__global__ void build_tiles_kernel(const int* __restrict__ start, int2* __restrict__ tiles) {
  int g = blockIdx.x * blockDim.x + threadIdx.x;
  if (g >= NGRP2) return;
  int nt[4] = {0, 0, 0, 0};
  for (int w = 0; w < 4; w++)
    for (int s = 0; s < MAXSETS; s++)
      tiles[(g * 4 + w) * MAXSETS + s] = make_int2(0, 0);
  int t = 0;
  for (int i = 0; i < GNODES; i++) {
    int na = g * GNODES + i;
    int nb = na + 1;
    if (na > NN) na = NN;
    if (nb > NN) nb = NN;
    int s = start[na], e = start[nb];
    for (int m0 = s; m0 < e; m0 += 16) {
      int w = t & 3;
      if (nt[w] < MAXSETS) {
        int c = e - m0; if (c > 16) c = 16;
        tiles[(g * 4 + w) * MAXSETS + nt[w]] = make_int2(i | (c << 16), m0);
        nt[w]++;
      }
      t++;
    }
  }
}

// ---------------- h0 (+ bf16 copy + msg-bias) ----------------
__global__ void h0_mb_kernel(const float* __restrict__ x, const float* __restrict__ fc1w,
                             const float* __restrict__ fc1b, const float* __restrict__ k3b,
                             float* __restrict__ h, unsigned short* __restrict__ hbf,
                             float* __restrict__ mb) {
  int wave = threadIdx.x >> 6, lane = threadIdx.x & 63;
  int n = blockIdx.x * 4 + wave;
  if (n >= NN) return;
  float v = x[n] * fc1w[lane] + fc1b[lane];
  h[n * 64 + lane] = v;
  hbf[n * 64 + lane] = f2bf(v);
  float mbv = 0.f;
#pragma unroll
  for (int c = 0; c < 64; c++)
    mbv += __shfl(v, c, 64) * k3b[c * 64 + lane];
  mb[n * 64 + lane] = mbv;
}

// ---------------- fused per-depth message kernel (d-trick, FROZEN v12 structure) -----
// Best measured: ~367 us. launch_bounds(256,3): 84 VGPR, NO SPILLS. DO NOT CHANGE.
__global__ __launch_bounds__(256, 3)
void fused_msg_kernel(const unsigned short* __restrict__ hbf,
                      const unsigned short* __restrict__ e2p,
                      const unsigned short* __restrict__ kp3,
                      const int2* __restrict__ tiles,
                      const int* __restrict__ sorted_eid,
                      const int* __restrict__ dst,
                      const float* __restrict__ mb,
                      float* __restrict__ agg,
                      unsigned short* __restrict__ msgh,
                      float* __restrict__ msgf,
                      int msg_mode) {
  __shared__ unsigned short slab[GNODES * 512];  // 32 nodes x 16 o x 32 r = 32 KB
  const int tid = threadIdx.x, wave = tid >> 6, lane = tid & 63;
  const int l15 = lane & 15, quad = lane >> 4;
  const int oh = blockIdx.x & 3;           // XCD-pinned o-quarter
  const int ng = blockIdx.x >> 2;
  const int n0 = ng * GNODES;

  // ---- load static slots ----
  int s_node[MAXSETS], s_j[MAXSETS], s_cnt[MAXSETS], row_off[MAXSETS];
  const int2* tp = tiles + (ng * 4 + wave) * MAXSETS;
#pragma unroll
  for (int s2 = 0; s2 < MAXSETS; s2++) {
    int2 rec = tp[s2];
    s_node[s2] = rec.x & 0xffff;
    s_cnt[s2]  = rec.x >> 16;
    s_j[s2]    = rec.y;
    int c = s_cnt[s2];
    int sl = (l15 < c) ? l15 : (c > 0 ? c - 1 : 0);
    row_off[s2] = (s_j[s2] + sl) * 32 + quad * 8;  // within an rt-slice of e2p
  }

  f32x4 acc[MAXSETS];
#pragma unroll
  for (int s2 = 0; s2 < MAXSETS; s2++) { f32x4 z = {0.f, 0.f, 0.f, 0.f}; acc[s2] = z; }

  // producer B-frags (n = node), two 16-node halves, loop-invariant
  bf16x8 pb0[2], pb1[2];
#pragma unroll
  for (int g2 = 0; g2 < 2; g2++) {
    pb0[g2] = *(const bf16x8*)(hbf + (n0 + g2 * 16 + l15) * 64 + quad * 8);
    pb1[g2] = *(const bf16x8*)(hbf + (n0 + g2 * 16 + l15) * 64 + 32 + quad * 8);
  }

  for (int rt = 0; rt < 32; rt++) {
    __syncthreads();  // WAR: prev consume done before overwrite
    // prefetch consumer e2p frags (coalesced 1 KB wave-loads; overlap produce)
    const unsigned short* e2s = e2p + (size_t)rt * (E_PAD * 32);
    bf16x8 apre[MAXSETS];
#pragma unroll
    for (int s2 = 0; s2 < MAXSETS; s2++) {
      if (s_cnt[s2])  // wave-uniform
        apre[s2] = *(const bf16x8*)(e2s + row_off[s2]);
    }
    // ---- produce: 32 m-tiles (o_loc 16 x hh 2), wave covers 8, coalesced kp3 ----
#pragma unroll 4
    for (int u = 0; u < 8; u++) {
      int id = wave * 8 + u;
      int o_loc = id >> 1, hh = id & 1;
      int o = oh * 16 + o_loc;
      const unsigned short* blk = kp3 + (size_t)(((o * 32 + rt) * 2 + hh) * 2) * 512;
      bf16x8 a0 = *(const bf16x8*)(blk + lane * 8);          // chalf 0
      bf16x8 a1 = *(const bf16x8*)(blk + 512 + lane * 8);    // chalf 1
      int chunk_log = o_loc * 4 + hh * 2 + (quad >> 1);
      int phys = chunk_log ^ (l15 & 7);
#pragma unroll
      for (int g2 = 0; g2 < 2; g2++) {
        f32x4 c = {0.f, 0.f, 0.f, 0.f};
        c = __builtin_amdgcn_mfma_f32_16x16x32_bf16(a0, pb0[g2], c, 0, 0, 0);
        c = __builtin_amdgcn_mfma_f32_16x16x32_bf16(a1, pb1[g2], c, 0, 0, 0);
        // lane: node = g2*16 + l15, r_loc = hh*16 + quad*4 + reg -> one b64
        unsigned int w0 = (unsigned int)f2bf(c[0]) | ((unsigned int)f2bf(c[1]) << 16);
        unsigned int w1 = (unsigned int)f2bf(c[2]) | ((unsigned int)f2bf(c[3]) << 16);
        uint2* p = (uint2*)((char*)slab + (g2 * 16 + l15) * 1024 + phys * 16 + (quad & 1) * 8);
        uint2 w; w.x = w0; w.y = w1;
        *p = w;
      }
    }
    __syncthreads();  // RAW: slab ready
    // ---- consume: static slots, one k=32 MFMA each ----
#pragma unroll
    for (int s2 = 0; s2 < MAXSETS; s2++) {
      if (s_cnt[s2] == 0) continue;  // wave-uniform
      int node = s_node[s2];
      const char* nb = (const char*)slab + node * 1024;
      bf16x8 b = *(const bf16x8*)(nb + (((l15 * 4 + quad) ^ (node & 7)) * 16));
      acc[s2] = __builtin_amdgcn_mfma_f32_16x16x32_bf16(apre[s2], b, acc[s2], 0, 0, 0);
    }
  }

  // ---- epilogue (static slots), o-quarter slice ----
#pragma unroll
  for (int s2 = 0; s2 < MAXSETS; s2++) {
    if (s_cnt[s2] == 0) continue;  // wave-uniform
    float mbv = mb[(n0 + s_node[s2]) * 64 + oh * 16 + l15];
#pragma unroll
    for (int reg = 0; reg < 4; reg++) {
      int mloc = quad * 4 + reg;
      if (mloc < s_cnt[s2]) {
        int p = s_j[s2] + mloc;  // src-sorted position
        float v = acc[s2][reg] + mbv;
        if (msg_mode == 2) {
          __builtin_nontemporal_store(v, &msgf[p * 64 + oh * 16 + l15]);
        } else if (msg_mode == 1) {
          __builtin_nontemporal_store(f2bf(v), &msgh[p * 64 + oh * 16 + l15]);
        } else {
          int d = dst[sorted_eid[p]];
          atomicAdd(&agg[d * 64 + oh * 16 + l15], v);
        }
      }
    }
  }
}

// -------- gather msg rows by dst-CSR + full node update (+hbf/mb for next depth) --------
__global__ void scatter_update_mb_kernel(const unsigned short* __restrict__ msgh,
                                         const float* __restrict__ msgf,
                                         const int* __restrict__ startd,
                                         const int* __restrict__ sid2,
                                         const float* __restrict__ h,
                                         const float* __restrict__ root,
                                         const float* __restrict__ convb,
                                         const float* __restrict__ k3b,
                                         float* __restrict__ hout,
                                         unsigned short* __restrict__ hbf,
                                         float* __restrict__ mb,
                                         int do_relu, int msg_mode) {
  int wave = threadIdx.x >> 6, lane = threadIdx.x & 63;
  int n = blockIdx.x * 4 + wave;
  if (n >= NN) return;
  float hv = h[n * 64 + lane];
  float racc = 0.f;
#pragma unroll
  for (int c = 0; c < 64; c++)
    racc += __shfl(hv, c, 64) * root[c * 64 + lane];
  int js = startd[n], je = startd[n + 1];
  float sum = 0.f;
  if (msg_mode == 2) {
    for (int j = js; j < je; j++) { int p = sid2[j]; sum += msgf[p * 64 + lane]; }
  } else {
    for (int j = js; j < je; j++) { int p = sid2[j]; sum += bf2f(msgh[p * 64 + lane]); }
  }
  float inv = (je > js) ? 1.0f / (float)(je - js) : 0.f;
  float v = sum * inv + racc + convb[lane];
  if (do_relu) v = fmaxf(v, 0.f);
  hout[n * 64 + lane] = v;
  hbf[n * 64 + lane] = f2bf(v);
  float mbv = 0.f;
#pragma unroll
  for (int c = 0; c < 64; c++)
    mbv += __shfl(v, c, 64) * k3b[c * 64 + lane];
  mb[n * 64 + lane] = mbv;
}

// -------- update (+ bf16 copy + msg-bias), atomic-agg variant --------
__global__ void update_mb_kernel(const float* __restrict__ h, const float* __restrict__ agg,
                                 const float* __restrict__ deg, const float* __restrict__ root,
                                 const float* __restrict__ convb, const float* __restrict__ k3b,
                                 float* __restrict__ hout, unsigned short* __restrict__ hbf,
                                 float* __restrict__ mb, int do_relu) {
  int wave = threadIdx.x >> 6, lane = threadIdx.x & 63;
  int n = blockIdx.x * 4 + wave;
  if (n >= NN) return;
  float hv = h[n * 64 + lane];
  float acc = 0.f;
#pragma unroll
  for (int c = 0; c < 64; c++)
    acc += __shfl(hv, c, 64) * root[c * 64 + lane];
  float dg = deg[n];
  float inv = dg > 0.f ? 1.0f / dg : 0.f;
  float v = agg[n * 64 + lane] * inv + acc + convb[lane];
  if (do_relu) v = fmaxf(v, 0.f);
  hout[n * 64 + lane] = v;
  hbf[n * 64 + lane] = f2bf(v);
  float mbv = 0.f;
#pragma unroll
  for (int c = 0; c < 64; c++)
    mbv += __shfl(v, c, 64) * k3b[c * 64 + lane];
  mb[n * 64 + lane] = mbv;
}

// ---------------- fallback-path kernels (round-2 Plan C, proven) ----------------
__global__ void h0_kernel(const float* __restrict__ x, const float* __restrict__ fc1w,
                          const float* __restrict__ fc1b, float* __restrict__ h) {
  int idx = blockIdx.x * blockDim.x + threadIdx.x;
  if (idx >= NN * WIDTH) return;
  int n = idx >> 6, w = idx & 63;
  h[idx] = x[n] * fc1w[w] + fc1b[w];
}

__global__ void msg_kernel(const float* __restrict__ h, const unsigned short* __restrict__ Wc,
                           const int* __restrict__ src, const int* __restrict__ dst,
                           float* __restrict__ agg, int e0, int e_end) {
  int wave = threadIdx.x >> 6;
  int lane = threadIdx.x & 63;
  int e = e0 + blockIdx.x * 4 + wave;
  if (e >= e_end) return;
  int s = src[e], d = dst[e];
  float hv = h[s * WIDTH + lane];
  const unsigned short* We = Wc + (long long)(e - e0) * 4096;
  float acc = 0.f;
#pragma unroll
  for (int c = 0; c < 64; c++) {
    float hs = __shfl(hv, c, 64);
    acc += hs * bf2f(We[c * 64 + lane]);
  }
  atomicAdd(&agg[d * WIDTH + lane], acc);
}

__global__ void update_kernel(const float* __restrict__ h, const float* __restrict__ agg,
                              const float* __restrict__ deg, const float* __restrict__ root,
                              const float* __restrict__ convb, float* __restrict__ hout,
                              int do_relu) {
  int wave = threadIdx.x >> 6, lane = threadIdx.x & 63;
  int n = blockIdx.x * 4 + wave;
  if (n >= NN) return;
  float hv = h[n * WIDTH + lane];
  float acc = 0.f;
#pragma unroll
  for (int c = 0; c < 64; c++)
    acc += __shfl(hv, c, 64) * root[c * WIDTH + lane];
  float dg = deg[n];
  float inv = dg > 0.f ? 1.0f / dg : 0.f;
  float v = agg[n * WIDTH + lane] * inv + acc + convb[lane];
  if (do_relu) v = fmaxf(v, 0.f);
  hout[n * WIDTH + lane] = v;
}

__global__ void fc2_kernel(const float* __restrict__ h, const float* __restrict__ fc2w,
                           const float* __restrict__ fc2b, float* __restrict__ out) {
  int wave = threadIdx.x >> 6, lane = threadIdx.x & 63;
  int n = blockIdx.x * 4 + wave;
  if (n >= NN) return;
  float v = h[n * WIDTH + lane] * fc2w[lane];
#pragma unroll
  for (int off = 32; off > 0; off >>= 1) v += __shfl_down(v, off, 64);
  if (lane == 0) out[n] = v + fc2b[0];
}

extern "C" void kernel_launch(void* const* d_in, const int* in_sizes, int n_in,
                              void* d_out, int out_size, void* d_ws, size_t ws_size,
                              hipStream_t stream) {
  const float* x     = (const float*)d_in[0];
  const int*   ei    = (const int*)d_in[1];
  const float* ea    = (const float*)d_in[2];
  const float* fc1w  = (const float*)d_in[3];
  const float* fc1b  = (const float*)d_in[4];
  const float* k1w   = (const float*)d_in[5];
  const float* k1b   = (const float*)d_in[6];
  const float* k2w   = (const float*)d_in[7];
  const float* k2b   = (const float*)d_in[8];
  const float* k3w   = (const float*)d_in[9];
  const float* k3b   = (const float*)d_in[10];
  const float* root  = (const float*)d_in[11];
  const float* convb = (const float*)d_in[12];
  const float* fc2w  = (const float*)d_in[13];
  const float* fc2b  = (const float*)d_in[14];
  float* out = (float*)d_out;
  const int* src = ei;
  const int* dst = ei + NE;

  char* ws = (char*)d_ws;
  size_t off = 0;
  auto alloc = [&](size_t bytes) -> char* {
    char* p = ws + off; off = (off + bytes + 255) & ~(size_t)255; return p;
  };
  auto al = [](size_t x) { return (x + 255) & ~(size_t)255; };

  // ---- common ----
  unsigned short* k2wT = (unsigned short*)alloc((size_t)KW * KW * 2);
  float* ha  = (float*)alloc((size_t)NN * WIDTH * 4);
  float* hb  = (float*)alloc((size_t)NN * WIDTH * 4);
  float* agg = (float*)alloc((size_t)NN * WIDTH * 4);
  float* deg = (float*)alloc((size_t)NN * 4);
  if (ws_size < off + 4096) return;

  const size_t PT_CH = 128 * KW * 2;  // 262144

  size_t sz_kpt  = (size_t)(64 << 16) * 2;     // kp3: 8.39 MB
  size_t sz_mb   = (size_t)NN * 64 * 4;
  size_t sz_hbf  = (size_t)NN_PAD * 64 * 2;
  size_t sz_cnt  = (size_t)NN * 4;
  size_t sz_st   = (size_t)(NN + 1) * 4;
  size_t sz_sid  = (size_t)NE * 4;
  size_t sz_e2   = (size_t)E_PAD * KW * 2;     // e2p
  size_t sz_tiles = (size_t)NGRP2 * 4 * MAXSETS * 8;

  size_t core = al(sz_kpt) + al(sz_mb) + al(sz_hbf) + al(sz_cnt) + al(sz_st) + al(sz_cnt)
              + al(sz_sid) + al(sz_e2) + al(sz_tiles) + al(sz_sid) /*pose*/;
  size_t msg_csr = al(sz_cnt) + al(sz_st) + al(sz_cnt) + al(sz_sid);
  size_t e1c_min = al((size_t)8 * PT_CH);

  // v15: PREFER bf16 msg buffer (mode 1) — halves fused-epilogue stores and the
  // scatter_update gather segments vs fp32 (mode 2). Accuracy headroom verified:
  // absmax 9.8e-4 (fp32 msg) vs 3.85e-3 threshold; bf16 msg adds ~0.2% rel.
  int msg_mode;  // 1 = bf16 msg buffer, 0 = atomic agg, -1 = Plan C
  if (ws_size >= off + core + msg_csr + al((size_t)NE * 64 * 2) + e1c_min)  msg_mode = 1;
  else if (ws_size >= off + core + e1c_min + 8192)                          msg_mode = 0;
  else                                                                      msg_mode = -1;

  if (msg_mode >= 0) {
    // ================= FUSED d-TRICK PATH (v15 = v14 + bf16 msg) =================
    unsigned short* kp3 = (unsigned short*)alloc(sz_kpt);
    float* mb   = (float*)alloc(sz_mb);
    unsigned short* hbf = (unsigned short*)alloc(sz_hbf);
    int* cnt    = (int*)alloc(sz_cnt);
    int* starta = (int*)alloc(sz_st);
    int* cursor = (int*)alloc(sz_cnt);
    int* sid    = (int*)alloc(sz_sid);
    unsigned short* e2p = (unsigned short*)alloc(sz_e2);
    int2* tiles = (int2*)alloc(sz_tiles);
    int* pose   = (int*)alloc(sz_sid);
    int* cnt2 = nullptr; int* startd = nullptr;
    int* cursor2 = nullptr; int* sid2 = nullptr;
    unsigned short* msgh = nullptr; float* msgf = nullptr;
    if (msg_mode >= 1) {
      cnt2    = (int*)alloc(sz_cnt);
      startd  = (int*)alloc(sz_st);
      cursor2 = (int*)alloc(sz_cnt);
      sid2    = (int*)alloc(sz_sid);
      msgh    = (unsigned short*)alloc((size_t)NE * 64 * 2);
    }
    size_t left = ws_size - off;
    int TC = (int)(left / PT_CH); if (TC > MT_ALL) TC = MT_ALL;
    unsigned short* e1c = (unsigned short*)alloc((size_t)TC * PT_CH);

    convert_transpose_kernel<<<(KW * KW) / 256, 256, 0, stream>>>(k2w, k2wT, KW, KW);
    build_kpt3_kernel<<<(64 << 16) / 256, 256, 0, stream>>>(k3w, kp3);
    hipMemsetAsync(cnt, 0, sz_cnt, stream);
    count_kernel<<<(NE + 255) / 256, 256, 0, stream>>>(src, cnt, NE);
    scan_kernel<<<1, 1024, 0, stream>>>(cnt, starta, cursor);
    scatter_kernel<<<(NE + 255) / 256, 256, 0, stream>>>(src, cursor, sid, pose, NE);
    build_tiles_kernel<<<(NGRP2 + 255) / 256, 256, 0, stream>>>(starta, tiles);
    if (msg_mode >= 1) {
      hipMemsetAsync(cnt2, 0, sz_cnt, stream);
      count_kernel<<<(NE + 255) / 256, 256, 0, stream>>>(dst, cnt2, NE);
      scan_kernel<<<1, 1024, 0, stream>>>(cnt2, startd, cursor2);
      scatter2_kernel<<<(NE + 255) / 256, 256, 0, stream>>>(dst, cursor2, pose, sid2, NE);
    } else {
      hipMemsetAsync(deg, 0, (size_t)NN * 4, stream);
      deg_kernel<<<(NE + 255) / 256, 256, 0, stream>>>(dst, deg, NE);
    }
    h0_mb_kernel<<<(NN + 3) / 4, 256, 0, stream>>>(x, fc1w, fc1b, k3b, ha, hbf, mb);
    // e1 gathered via sid (sorted order) -> gemm2 writes e2p contiguously
    for (int t0 = 0; t0 < MT_ALL; t0 += TC) {
      int tc = (MT_ALL - t0 < TC) ? (MT_ALL - t0) : TC;
      gemm1_kernel<<<tc * 128 / G1E, 256, 0, stream>>>(ea, k1w, k1b, sid, e1c, t0 * 128, NE);
      gemm_bt_kernel<<<tc * (KW / 128), 256, 0, stream>>>(
          e1c, k2wT, k2b, e2p, t0 * 128, KW, KW, tc, 1, 1);
    }
    float* hc = ha; float* hn = hb;
    for (int k = 0; k < DEPTH; k++) {
      if (msg_mode == 0) hipMemsetAsync(agg, 0, (size_t)NN * WIDTH * 4, stream);
      fused_msg_kernel<<<4 * NGRP2, 256, 0, stream>>>(
          hbf, e2p, kp3, tiles, sid, dst, mb, agg, msgh, msgf, msg_mode);
      if (msg_mode >= 1)
        scatter_update_mb_kernel<<<(NN + 3) / 4, 256, 0, stream>>>(
            msgh, msgf, startd, sid2, hc, root, convb, k3b, hn, hbf, mb,
            (k != DEPTH - 1) ? 1 : 0, msg_mode);
      else
        update_mb_kernel<<<(NN + 3) / 4, 256, 0, stream>>>(
            hc, agg, deg, root, convb, k3b, hn, hbf, mb, (k != DEPTH - 1) ? 1 : 0);
      float* t = hc; hc = hn; hn = t;
    }
    fc2_kernel<<<(NN + 3) / 4, 256, 0, stream>>>(hc, fc2w, fc2b, out);
  } else {
    // ================= FALLBACK: round-2 Plan C (proven) =================
    unsigned short* k3wT = (unsigned short*)alloc((size_t)4096 * KW * 2);
    size_t rem = (ws_size > off) ? ws_size - off : 0;
    const size_t PT_W = 128 * 4096 * 2;
    size_t per_tile = 2 * PT_CH + PT_W;
    long long tcl = (long long)(rem / per_tile);
    int TC = (tcl > 98) ? 98 : (int)tcl;
    if (TC < 1) return;
    unsigned short* e1c = (unsigned short*)alloc((size_t)TC * PT_CH);
    unsigned short* e2c = (unsigned short*)alloc((size_t)TC * PT_CH);
    unsigned short* Wc  = (unsigned short*)alloc((size_t)TC * PT_W);

    convert_transpose_kernel<<<(KW * KW) / 256, 256, 0, stream>>>(k2w, k2wT, KW, KW);
    convert_transpose_kernel<<<(KW * 4096) / 256, 256, 0, stream>>>(k3w, k3wT, KW, 4096);
    hipMemsetAsync(deg, 0, (size_t)NN * 4, stream);
    deg_kernel<<<(NE + 255) / 256, 256, 0, stream>>>(dst, deg, NE);
    h0_kernel<<<(NN * WIDTH) / 256, 256, 0, stream>>>(x, fc1w, fc1b, ha);

    float* hc = ha; float* hn = hb;
    for (int k = 0; k < DEPTH; k++) {
      hipMemsetAsync(agg, 0, (size_t)NN * WIDTH * 4, stream);
      for (int t0 = 0; t0 < MT_ALL; t0 += TC) {
        int tc = (MT_ALL - t0 < TC) ? (MT_ALL - t0) : TC;
        gemm1_kernel<<<tc * 128 / G1E, 256, 0, stream>>>(ea, k1w, k1b, nullptr, e1c,
                                                         t0 * 128, NE);
        gemm_bt_kernel<<<tc * (KW / 128), 256, 0, stream>>>(e1c, k2wT, k2b, e2c,
                                                            0, KW, KW, tc, 1, 0);
        gemm_bt_kernel<<<tc * (4096 / 128), 256, 0, stream>>>(e2c, k3wT, k3b, Wc,
                                                              0, 4096, KW, tc, 0, 0);
        int e0 = t0 * 128;
        int e_end = (t0 + tc) * 128; if (e_end > NE) e_end = NE;
        if (e_end > e0)
          msg_kernel<<<(e_end - e0 + 3) / 4, 256, 0, stream>>>(hc, Wc, src, dst, agg, e0, e_end);
      }
      update_kernel<<<(NN + 3) / 4, 256, 0, stream>>>(hc, agg, deg, root, convb, hn,
                                                      (k != DEPTH - 1) ? 1 : 0);
      float* t = hc; hc = hn; hn = t;
    }
    fc2_kernel<<<(NN + 3) / 4, 256, 0, stream>>>(hc, fc2w, fc2b, out);
  }
}